// Round 1
// baseline (190.654 us; speedup 1.0000x reference)
//
#include <hip/hip_runtime.h>
#include <math.h>

// Problem constants (fixed by setup_inputs)
#define Nn 4
#define Ll 4096
#define Ss 256
#define Cc 256
#define FC 8
#define SC 32

#define ASTR 68                         // A-tile LDS stride (sim_k)
#define BSTR 132                        // B-tile LDS stride (sim_k)
#define PHI(k) ((((k) >> 3) & 3) << 2)  // row-XOR swizzle (const per k-octet)

typedef __attribute__((ext_vector_type(8))) short short8;     // 8 bf16 frag
typedef __attribute__((ext_vector_type(8))) _Float16 half8;   // 8 f16 frag
typedef __attribute__((ext_vector_type(4))) float f32x4;      // MFMA acc

__device__ __forceinline__ unsigned short f2bf(float x) {   // RTNE f32->bf16
  unsigned int u = __float_as_uint(x);
  return (unsigned short)((u + 0x7FFFu + ((u >> 16) & 1u)) >> 16);
}

// ---------------------------------------------------------------------------
// ROUND-11: fp32-accurate f16-split GEMM on matrix cores.
// x = hi + lo/2048 + eps, |eps| <= 2^-22 |x|:
//   hi = (f16)x (RTNE);  r = x - (float)hi is EXACT in fp32 (within 2^-11
//   relative -> Sterbenz);  lo = (f16)(r * 2048) never subnormal.
// acc1 accumulates hi*hi (bias-seeded); acc2 accumulates hi*lo + lo*hi;
// result = acc1 + acc2 * 2^-11.  3 MFMA passes ~= fp32 accuracy (worst-case
// ~7e-7 rel, rms ~1e-7 -- same order as fp32 re-association noise already in
// the verified kernel, so the sim argmax is not perturbed beyond baseline).
// ---------------------------------------------------------------------------
__device__ __forceinline__ void split8v(float4 a, float4 b,
                                        half8& hi, half8& lo) {
  float v[8] = {a.x, a.y, a.z, a.w, b.x, b.y, b.z, b.w};
#pragma unroll
  for (int i = 0; i < 8; i++) {
    float x = v[i];
    _Float16 h = (_Float16)x;          // v_cvt_f16_f32 (RTNE)
    float r = (x - (float)h) * 2048.f; // exact residual, pre-scaled
    hi[i] = h;
    lo[i] = (_Float16)r;
  }
}

// 64x32 per-wave tile, K=256, no LDS (out_mfma_k-proven load pattern).
// A rows m0w..m0w+63 (mi*16 + l15), B rows (=out cols) n0w..n0w+31.
// k chunk per lane: kt*32 + quad*8, 8 contiguous floats.
__device__ __forceinline__ void mfma_core_f32(
    const float* __restrict__ A, const float* __restrict__ B,
    const float* __restrict__ bias, size_t m0w, int n0w, int lane,
    f32x4 acc1[4][2], f32x4 acc2[4][2]) {
  int quad = lane >> 4, l15 = lane & 15;
#pragma unroll
  for (int ni = 0; ni < 2; ni++) {
    float bv = bias[n0w + ni * 16 + l15];
    f32x4 ci = {bv, bv, bv, bv};
    f32x4 zz = {0.f, 0.f, 0.f, 0.f};
#pragma unroll
    for (int mi = 0; mi < 4; mi++) { acc1[mi][ni] = ci; acc2[mi][ni] = zz; }
  }
#pragma unroll 1                        // keep VGPRs bounded (~2 waves/SIMD)
  for (int kt = 0; kt < 8; kt++) {
    int k0 = kt * 32 + quad * 8;
    half8 Ah[4], Al[4];
#pragma unroll
    for (int mi = 0; mi < 4; mi++) {
      const float* p = A + (m0w + mi * 16 + l15) * Cc + k0;
      split8v(*(const float4*)p, *(const float4*)(p + 4), Ah[mi], Al[mi]);
    }
#pragma unroll
    for (int ni = 0; ni < 2; ni++) {    // B loaded per-ni: lower reg pressure
      const float* p = B + (size_t)(n0w + ni * 16 + l15) * Cc + k0;
      half8 Bh, Bl;
      split8v(*(const float4*)p, *(const float4*)(p + 4), Bh, Bl);
#pragma unroll
      for (int mi = 0; mi < 4; mi++) {
        acc1[mi][ni] = __builtin_amdgcn_mfma_f32_16x16x32_f16(
            Ah[mi], Bh, acc1[mi][ni], 0, 0, 0);
        acc2[mi][ni] = __builtin_amdgcn_mfma_f32_16x16x32_f16(
            Ah[mi], Bl, acc2[mi][ni], 0, 0, 0);
        acc2[mi][ni] = __builtin_amdgcn_mfma_f32_16x16x32_f16(
            Al[mi], Bh, acc2[mi][ni], 0, 0, 0);
      }
    }
  }
}

// ---------------------------------------------------------------------------
// Fused projections. Blocks 0..511: xn = x0 @ W0^T + b0 (M=16384, N=256,
// block tile 128x64, 4 waves of 64x32).  Blocks 512..575: c1 = center1 @
// W1^T + b1 (M=1024, N=512) with split/l2norm epilogue -> cpn (normalized
// point half), cval (raw value half).  A 32-col wave tile lies entirely in
// one half (n0w multiple of 32), so the norm is a 16-lane shfl reduce.
// ---------------------------------------------------------------------------
__global__ __launch_bounds__(256) void proj_mfma_k(
    const float* __restrict__ x0, const float* __restrict__ W0,
    const float* __restrict__ b0, const float* __restrict__ center1,
    const float* __restrict__ W1, const float* __restrict__ b1,
    float* __restrict__ xn, float* __restrict__ cpn, float* __restrict__ cval) {
  int t = threadIdx.x;
  int wave = t >> 6, lane = t & 63;
  int quad = lane >> 4, l15 = lane & 15;
  int b = blockIdx.x;
  f32x4 acc1[4][2], acc2[4][2];

  if (b < 512) {
    size_t m0 = (size_t)(b >> 2) * 128 + (size_t)(wave & 1) * 64;
    int n0 = (b & 3) * 64 + (wave >> 1) * 32;
    mfma_core_f32(x0, W0, b0, m0, n0, lane, acc1, acc2);
#pragma unroll
    for (int mi = 0; mi < 4; mi++) {
#pragma unroll
      for (int reg = 0; reg < 4; reg++) {
        size_t row = m0 + mi * 16 + quad * 4 + reg;
        float* orow = xn + row * Cc + n0;
#pragma unroll
        for (int ni = 0; ni < 2; ni++)
          orow[ni * 16 + l15] =
              acc1[mi][ni][reg] + acc2[mi][ni][reg] * (1.f / 2048.f);
      }
    }
  } else {
    int b2 = b - 512;
    size_t m0 = (size_t)(b2 >> 3) * 128 + (size_t)(wave & 1) * 64;
    int n0 = (b2 & 7) * 64 + (wave >> 1) * 32;   // N=512
    mfma_core_f32(center1, W1, b1, m0, n0, lane, acc1, acc2);
    int f = n0 >> 6;                   // fiber
    bool point = (n0 & 32) == 0;       // cols (n0&63)+0..31: point iff ==0
#pragma unroll
    for (int mi = 0; mi < 4; mi++) {
#pragma unroll
      for (int reg = 0; reg < 4; reg++) {
        int row = (int)m0 + mi * 16 + quad * 4 + reg;  // 0..1023 = nI*256+s
        int nI = row >> 8, s = row & 255;
        float v0 = acc1[mi][0][reg] + acc2[mi][0][reg] * (1.f / 2048.f);
        float v1 = acc1[mi][1][reg] + acc2[mi][1][reg] * (1.f / 2048.f);
        size_t base = (((size_t)nI * FC + f) * Ss + s) * SC;
        if (point) {
          float ss = v0 * v0 + v1 * v1;     // 2 elems/lane x 16 lanes = 32
          ss += __shfl_xor(ss, 1, 64);
          ss += __shfl_xor(ss, 2, 64);
          ss += __shfl_xor(ss, 4, 64);
          ss += __shfl_xor(ss, 8, 64);      // full row in every quad lane
          float rin = 1.f / fmaxf(sqrtf(ss), 1e-12f);
          cpn[base + l15] = v0 * rin;
          cpn[base + 16 + l15] = v1 * rin;
        } else {
          cval[base + l15] = v0;
          cval[base + 16 + l15] = v1;
        }
      }
    }
  }
}

// ---------------------------------------------------------------------------
// sim: per block one (n,f), 64 l-rows; centers as TWO tiles of 128 looped
// in-block. 128 threads, thread 8 rows {4tr+i, 32+4tr+i} x 8 centers
// {4tc+c, 64+4tc+c} per tile. G=4 k-batched LDS reads. X rows l2-normalized
// at staging. Argmax of a*sim+b folded across tiles in-thread, then 16-lane
// shfl_xor reduce (min-index tie). Gather c_value, scale by sigmoid(max),
// write dispatched IN PLACE over xn.                       (UNCHANGED)
// ---------------------------------------------------------------------------
__global__ __launch_bounds__(128) void sim_k(
    float* __restrict__ xn, const float* __restrict__ cpn,
    const float* __restrict__ cval, const float* __restrict__ alphap,
    const float* __restrict__ betap) {
  __shared__ float Xs[32 * ASTR];  //  8.7 KB (rows 0..63)
  __shared__ float Cs[32 * BSTR];  // 16.9 KB (128 centers per tile)
  int t = threadIdx.x;
  int tc = t & 15, tr = t >> 4;    // tr in [0,8)
  int lt = blockIdx.x & 63;
  int nf = blockIdx.x >> 6;        // 0..31
  int f = nf & 7, nI = nf >> 3;
  int l0 = lt * 64;
  const float* cp = cpn + (size_t)nf * Ss * SC;

  // stage x rows 64x32, l2-normalized (8-lane shfl per row)
  {
    int jq = t & 7, r0 = 4 * (t >> 3);  // rows r0..r0+3
    int ph = ((jq >> 1) & 3) << 2;
    float4 v[4];
    float ssq[4];
#pragma unroll
    for (int i = 0; i < 4; i++) {
      v[i] = *(const float4*)(xn + ((size_t)nI * Ll + l0 + r0 + i) * Cc + f * SC + 4 * jq);
      ssq[i] = v[i].x * v[i].x + v[i].y * v[i].y + v[i].z * v[i].z + v[i].w * v[i].w;
    }
#pragma unroll
    for (int m = 1; m <= 4; m <<= 1)
#pragma unroll
      for (int i = 0; i < 4; i++) ssq[i] += __shfl_xor(ssq[i], m, 64);
#pragma unroll
    for (int i = 0; i < 4; i++) {
      float rin = 1.f / fmaxf(sqrtf(ssq[i]), 1e-12f);
      v[i].x *= rin; v[i].y *= rin; v[i].z *= rin; v[i].w *= rin;
    }
#pragma unroll
    for (int q = 0; q < 4; q++) {
      float4 w;
      w.x = ((const float*)&v[0])[q]; w.y = ((const float*)&v[1])[q];
      w.z = ((const float*)&v[2])[q]; w.w = ((const float*)&v[3])[q];
      *(float4*)&Xs[(4 * jq + q) * ASTR + (r0 ^ ph)] = w;
    }
  }

  float a = alphap[0], bt = betap[0];
  float best[8];
  int bi[8];
#pragma unroll
  for (int i = 0; i < 8; i++) { best[i] = -3.0e38f; bi[i] = 0; }

#pragma unroll 1
  for (int st = 0; st < 2; st++) {
    if (st) __syncthreads();  // previous tile's reads complete
    // stage 128 centers x 32 k (2 reg-transposed 4x4 blocks per thread)
#pragma unroll
    for (int it = 0; it < 2; it++) {
      int idx = t + 128 * it;
      int jq = idx & 7, c0 = 4 * (idx >> 3);  // c0 in {0..124}
      int ph = ((jq >> 1) & 3) << 2;
      float4 v[4];
#pragma unroll
      for (int i = 0; i < 4; i++)
        v[i] = *(const float4*)(cp + (size_t)(st * 128 + c0 + i) * SC + 4 * jq);
#pragma unroll
      for (int q = 0; q < 4; q++) {
        float4 w;
        w.x = ((const float*)&v[0])[q]; w.y = ((const float*)&v[1])[q];
        w.z = ((const float*)&v[2])[q]; w.w = ((const float*)&v[3])[q];
        *(float4*)&Cs[(4 * jq + q) * BSTR + (c0 ^ ph)] = w;
      }
    }
    __syncthreads();

    float acc[8][8];
#pragma unroll
    for (int i = 0; i < 8; i++)
#pragma unroll
      for (int c = 0; c < 8; c++) acc[i][c] = 0.f;

    int ia0 = 4 * tr, ib0 = 4 * tc;
#pragma unroll 1
    for (int kb = 0; kb < 32; kb += 4) {
      int ph = PHI(kb);
      int ja = ia0 ^ ph, jb = ib0 ^ ph;
      float4 A0[4], A1[4], B0[4], B1[4];
#pragma unroll
      for (int u = 0; u < 4; u++) {
        const float* ab = &Xs[(kb + u) * ASTR];
        const float* bb = &Cs[(kb + u) * BSTR];
        A0[u] = *(const float4*)&ab[ja];
        A1[u] = *(const float4*)&ab[32 + ja];
        B0[u] = *(const float4*)&bb[jb];
        B1[u] = *(const float4*)&bb[64 + jb];
      }
#pragma unroll
      for (int u = 0; u < 4; u++) {
        const float* af0 = (const float*)&A0[u];
        const float* af1 = (const float*)&A1[u];
        const float* bf0 = (const float*)&B0[u];
        const float* bf1 = (const float*)&B1[u];
#pragma unroll
        for (int i = 0; i < 4; i++) {
#pragma unroll
          for (int c = 0; c < 4; c++) {
            acc[i][c]         = fmaf(af0[i], bf0[c], acc[i][c]);
            acc[i][c + 4]     = fmaf(af0[i], bf1[c], acc[i][c + 4]);
            acc[i + 4][c]     = fmaf(af1[i], bf0[c], acc[i + 4][c]);
            acc[i + 4][c + 4] = fmaf(af1[i], bf1[c], acc[i + 4][c + 4]);
          }
        }
      }
    }

    // fold argmax (in-thread s strictly increasing across c and tiles)
#pragma unroll
    for (int i = 0; i < 8; i++) {
#pragma unroll
      for (int c = 0; c < 8; c++) {
        float tv = fmaf(a, acc[i][c], bt);
        int s = st * 128 + ((c < 4) ? (4 * tc + c) : (64 + 4 * tc + (c - 4)));
        if (tv > best[i]) { best[i] = tv; bi[i] = s; }
      }
    }
  }

#pragma unroll
  for (int i = 0; i < 8; i++) {
    int row = (i < 4) ? (4 * tr + i) : (32 + 4 * tr + (i - 4));
    float bv = best[i];
    int ix = bi[i];
#pragma unroll
    for (int m = 1; m <= 8; m <<= 1) {  // reduce across the 16 tc-lanes
      float ov = __shfl_xor(bv, m, 64);
      int oi = __shfl_xor(ix, m, 64);
      if (ov > bv || (ov == bv && oi < ix)) { bv = ov; ix = oi; }
    }
    float mv = 1.f / (1.f + expf(-bv));
    const float* cvp = cval + ((size_t)nf * Ss + ix) * SC;
    float* orow = xn + ((size_t)nI * Ll + l0 + row) * Cc + f * SC;
    orow[tc] = cvp[tc] * mv;
    orow[tc + 16] = cvp[tc + 16] * mv;
  }
}

// ---------------------------------------------------------------------------
// out = dispatched @ Wm^T + bm via bf16 MFMA, NO LDS.        (UNCHANGED)
// ---------------------------------------------------------------------------
__global__ __launch_bounds__(256) void out_mfma_k(
    const float* __restrict__ xn, const float* __restrict__ Wm,
    const float* __restrict__ bm, float* __restrict__ out) {
  int t = threadIdx.x;
  int wave = t >> 6, lane = t & 63;
  int quad = lane >> 4, l15 = lane & 15;
  size_t m0 = (size_t)(blockIdx.x >> 1) * 128 + (wave & 1) * 64;
  int n0 = (blockIdx.x & 1) * 128 + (wave >> 1) * 64;

  f32x4 acc[4][4];
#pragma unroll
  for (int ni = 0; ni < 4; ni++) {
    float bv = bm[n0 + ni * 16 + l15];
    f32x4 ci = {bv, bv, bv, bv};
#pragma unroll
    for (int mi = 0; mi < 4; mi++) acc[mi][ni] = ci;
  }

  for (int kt = 0; kt < 8; kt++) {
    int k0 = kt * 32 + quad * 8;
    short8 Af[4], Bf[4];
#pragma unroll
    for (int mi = 0; mi < 4; mi++) {
      const float* p = xn + (m0 + mi * 16 + l15) * Cc + k0;
      float4 lo = *(const float4*)p;
      float4 hi = *(const float4*)(p + 4);
      short8 fr;
      fr[0] = (short)f2bf(lo.x); fr[1] = (short)f2bf(lo.y);
      fr[2] = (short)f2bf(lo.z); fr[3] = (short)f2bf(lo.w);
      fr[4] = (short)f2bf(hi.x); fr[5] = (short)f2bf(hi.y);
      fr[6] = (short)f2bf(hi.z); fr[7] = (short)f2bf(hi.w);
      Af[mi] = fr;
    }
#pragma unroll
    for (int ni = 0; ni < 4; ni++) {
      const float* p = Wm + (size_t)(n0 + ni * 16 + l15) * Cc + k0;
      float4 lo = *(const float4*)p;
      float4 hi = *(const float4*)(p + 4);
      short8 fr;
      fr[0] = (short)f2bf(lo.x); fr[1] = (short)f2bf(lo.y);
      fr[2] = (short)f2bf(lo.z); fr[3] = (short)f2bf(lo.w);
      fr[4] = (short)f2bf(hi.x); fr[5] = (short)f2bf(hi.y);
      fr[6] = (short)f2bf(hi.z); fr[7] = (short)f2bf(hi.w);
      Bf[ni] = fr;
    }
#pragma unroll
    for (int mi = 0; mi < 4; mi++)
#pragma unroll
      for (int ni = 0; ni < 4; ni++)
        acc[mi][ni] = __builtin_amdgcn_mfma_f32_16x16x32_bf16(
            Af[mi], Bf[ni], acc[mi][ni], 0, 0, 0);
  }

#pragma unroll
  for (int mi = 0; mi < 4; mi++) {
#pragma unroll
    for (int reg = 0; reg < 4; reg++) {
      size_t row = m0 + mi * 16 + quad * 4 + reg;
      float* orow = out + row * Cc + n0;
#pragma unroll
      for (int ni = 0; ni < 4; ni++)
        orow[ni * 16 + l15] = acc[mi][ni][reg];
    }
  }
}

// ---------------------------------------------------------------------------
extern "C" void kernel_launch(void* const* d_in, const int* in_sizes, int n_in,
                              void* d_out, int out_size, void* d_ws, size_t ws_size,
                              hipStream_t stream) {
  const float* x0      = (const float*)d_in[0];
  const float* center1 = (const float*)d_in[1];
  const float* W0      = (const float*)d_in[2];
  const float* b0      = (const float*)d_in[3];
  const float* W1      = (const float*)d_in[4];
  const float* b1      = (const float*)d_in[5];
  const float* Wm      = (const float*)d_in[6];
  const float* bm      = (const float*)d_in[7];
  const float* alpha   = (const float*)d_in[8];
  const float* beta    = (const float*)d_in[9];
  float* out = (float*)d_out;
  float* ws  = (float*)d_ws;

  float* xn   = ws;                              // 16 MB: x0p, then dispatched in-place
  float* cpn  = xn + (size_t)Nn * Ll * Cc;       // 1 MB
  float* cval = cpn + (size_t)Nn * FC * Ss * SC; // 1 MB  (total 18 MB)

  proj_mfma_k<<<dim3(576), dim3(256), 0, stream>>>(
      x0, W0, b0, center1, W1, b1, xn, cpn, cval);
  sim_k<<<dim3(32 * 64), dim3(128), 0, stream>>>(xn, cpn, cval, alpha, beta);
  out_mfma_k<<<dim3(256), dim3(256), 0, stream>>>(xn, Wm, bm, out);
}

// Round 3
// 181.726 us; speedup vs baseline: 1.0491x; 1.0491x over previous
//
#include <hip/hip_runtime.h>
#include <math.h>

// Problem constants (fixed by setup_inputs)
#define Nn 4
#define Ll 4096
#define Ss 256
#define Cc 256
#define FC 8
#define SC 32

#define ASTR 68                         // A-tile LDS stride (sim_k)
#define BSTR 132                        // B-tile LDS stride (sim_k)
#define PHI(k) ((((k) >> 3) & 3) << 2)  // row-XOR swizzle (const per k-octet)

typedef __attribute__((ext_vector_type(8))) short short8;     // 8 bf16 frag
typedef __attribute__((ext_vector_type(8))) _Float16 half8;   // 8 f16 frag
typedef __attribute__((ext_vector_type(4))) float f32x4;      // MFMA acc

__device__ __forceinline__ unsigned short f2bf(float x) {   // RTNE f32->bf16
  unsigned int u = __float_as_uint(x);
  return (unsigned short)((u + 0x7FFFu + ((u >> 16) & 1u)) >> 16);
}

// ---------------------------------------------------------------------------
// fp32-accurate f16-split GEMM on matrix cores (round-11, verified absmax
// 0.0078). x = hi + lo/2048 + eps, |eps| <= 2^-22 |x|.
// ROUND-12 CHANGE (resubmitted round-13; round-12 bench died in acquisition):
// proj was latency-bound (Mfma 4%, VALU 13%, HBM 12%, occ 10% -- NOTHING
// busy). Fix: register double-buffered prefetch across kt (named buffers,
// no dynamic indexing) + XCD-aware block swizzle so the 4 col-blocks
// sharing an A row-tile hit the same XCD L2 (FETCH 37.5MB -> ~20MB).
// ---------------------------------------------------------------------------
__device__ __forceinline__ void split8v(float4 a, float4 b,
                                        half8& hi, half8& lo) {
  float v[8] = {a.x, a.y, a.z, a.w, b.x, b.y, b.z, b.w};
#pragma unroll
  for (int i = 0; i < 8; i++) {
    float x = v[i];
    _Float16 h = (_Float16)x;          // v_cvt_f16_f32 (RTNE)
    float r = (x - (float)h) * 2048.f; // exact residual, pre-scaled
    hi[i] = h;
    lo[i] = (_Float16)r;
  }
}

#define PROJ_LOAD(Abuf, Bbuf, KOFF)                                     \
  {                                                                     \
    _Pragma("unroll")                                                   \
    for (int mi = 0; mi < 4; mi++) {                                    \
      const float* p = Ab + (size_t)mi * 16 * Cc + (KOFF);              \
      Abuf[mi][0] = *(const float4*)p;                                  \
      Abuf[mi][1] = *(const float4*)(p + 4);                            \
    }                                                                   \
    _Pragma("unroll")                                                   \
    for (int ni = 0; ni < 2; ni++) {                                    \
      const float* p = Bb + (size_t)ni * 16 * Cc + (KOFF);              \
      Bbuf[ni][0] = *(const float4*)p;                                  \
      Bbuf[ni][1] = *(const float4*)(p + 4);                            \
    }                                                                   \
  }

#define PROJ_COMPUTE(Abuf, Bbuf)                                        \
  {                                                                     \
    half8 Bh[2], Bl[2];                                                 \
    _Pragma("unroll")                                                   \
    for (int ni = 0; ni < 2; ni++)                                      \
      split8v(Bbuf[ni][0], Bbuf[ni][1], Bh[ni], Bl[ni]);                \
    _Pragma("unroll")                                                   \
    for (int mi = 0; mi < 4; mi++) {                                    \
      half8 Ah, Al;                                                     \
      split8v(Abuf[mi][0], Abuf[mi][1], Ah, Al);                        \
      _Pragma("unroll")                                                 \
      for (int ni = 0; ni < 2; ni++) {                                  \
        acc1[mi][ni] = __builtin_amdgcn_mfma_f32_16x16x32_f16(          \
            Ah, Bh[ni], acc1[mi][ni], 0, 0, 0);                         \
        acc2[mi][ni] = __builtin_amdgcn_mfma_f32_16x16x32_f16(          \
            Ah, Bl[ni], acc2[mi][ni], 0, 0, 0);                         \
        acc2[mi][ni] = __builtin_amdgcn_mfma_f32_16x16x32_f16(          \
            Al, Bh[ni], acc2[mi][ni], 0, 0, 0);                         \
      }                                                                 \
    }                                                                   \
  }

// 64x32 per-wave tile, K=256, no LDS. Software-pipelined: prefetch kt+1
// raw float4s (independent loads) while kt is split+MFMA'd. WAR deps on the
// named buffers keep program order; loads stay in flight across compute.
__device__ __forceinline__ void mfma_core_f32(
    const float* __restrict__ A, const float* __restrict__ B,
    const float* __restrict__ bias, size_t m0w, int n0w, int lane,
    f32x4 acc1[4][2], f32x4 acc2[4][2]) {
  int quad = lane >> 4, l15 = lane & 15;
#pragma unroll
  for (int ni = 0; ni < 2; ni++) {
    float bv = bias[n0w + ni * 16 + l15];
    f32x4 ci = {bv, bv, bv, bv};
    f32x4 zz = {0.f, 0.f, 0.f, 0.f};
#pragma unroll
    for (int mi = 0; mi < 4; mi++) { acc1[mi][ni] = ci; acc2[mi][ni] = zz; }
  }
  const float* Ab = A + (m0w + l15) * Cc + quad * 8;
  const float* Bb = B + (size_t)(n0w + l15) * Cc + quad * 8;

  float4 cA[4][2], cB[2][2], nA[4][2], nB[2][2];
  PROJ_LOAD(cA, cB, 0);
#pragma unroll 1
  for (int kt = 0; kt < 8; kt += 2) {
    PROJ_LOAD(nA, nB, (kt + 1) * 32);       // prefetch odd step
    PROJ_COMPUTE(cA, cB);
    if (kt < 6) PROJ_LOAD(cA, cB, (kt + 2) * 32);  // prefetch next even
    PROJ_COMPUTE(nA, nB);
  }
}

// ---------------------------------------------------------------------------
// Fused projections. Blocks 0..511: xn = x0 @ W0^T + b0 (M=16384, N=256).
// Block swizzle: r = (b&7) + 8*((b>>3)&15) row-tile (128 rows), cb = b>>7
// col-block; the 4 cb's of a row-tile share b%8 (same XCD), and one XCD's
// 16-row-tile working set (2MB) fits its 4MB L2 -> A fetched once.
// Blocks 512..575: c1 = center1 @ W1^T + b1 (M=1024, N=512) with split/
// l2norm epilogue -> cpn (normalized point half), cval (raw value half).
// ---------------------------------------------------------------------------
__global__ __launch_bounds__(256, 2) void proj_mfma_k(
    const float* __restrict__ x0, const float* __restrict__ W0,
    const float* __restrict__ b0, const float* __restrict__ center1,
    const float* __restrict__ W1, const float* __restrict__ b1,
    float* __restrict__ xn, float* __restrict__ cpn, float* __restrict__ cval) {
  int t = threadIdx.x;
  int wave = t >> 6, lane = t & 63;
  int quad = lane >> 4, l15 = lane & 15;
  int b = blockIdx.x;
  f32x4 acc1[4][2], acc2[4][2];

  if (b < 512) {
    int r = (b & 7) + 8 * ((b >> 3) & 15);  // row-tile 0..127 (XCD-local)
    int cb = b >> 7;                        // col-block 0..3
    size_t m0 = (size_t)r * 128 + (size_t)(wave & 1) * 64;
    int n0 = cb * 64 + (wave >> 1) * 32;
    mfma_core_f32(x0, W0, b0, m0, n0, lane, acc1, acc2);
#pragma unroll
    for (int mi = 0; mi < 4; mi++) {
#pragma unroll
      for (int reg = 0; reg < 4; reg++) {
        size_t row = m0 + mi * 16 + quad * 4 + reg;
        float* orow = xn + row * Cc + n0;
#pragma unroll
        for (int ni = 0; ni < 2; ni++)
          orow[ni * 16 + l15] =
              acc1[mi][ni][reg] + acc2[mi][ni][reg] * (1.f / 2048.f);
      }
    }
  } else {
    int b2 = b - 512;
    size_t m0 = (size_t)(b2 >> 3) * 128 + (size_t)(wave & 1) * 64;
    int n0 = (b2 & 7) * 64 + (wave >> 1) * 32;   // N=512
    mfma_core_f32(center1, W1, b1, m0, n0, lane, acc1, acc2);
    int f = n0 >> 6;                   // fiber
    bool point = (n0 & 32) == 0;       // cols (n0&63)+0..31: point iff ==0
#pragma unroll
    for (int mi = 0; mi < 4; mi++) {
#pragma unroll
      for (int reg = 0; reg < 4; reg++) {
        int row = (int)m0 + mi * 16 + quad * 4 + reg;  // 0..1023 = nI*256+s
        int nI = row >> 8, s = row & 255;
        float v0 = acc1[mi][0][reg] + acc2[mi][0][reg] * (1.f / 2048.f);
        float v1 = acc1[mi][1][reg] + acc2[mi][1][reg] * (1.f / 2048.f);
        size_t base = (((size_t)nI * FC + f) * Ss + s) * SC;
        if (point) {
          float ss = v0 * v0 + v1 * v1;     // 2 elems/lane x 16 lanes = 32
          ss += __shfl_xor(ss, 1, 64);
          ss += __shfl_xor(ss, 2, 64);
          ss += __shfl_xor(ss, 4, 64);
          ss += __shfl_xor(ss, 8, 64);      // full row in every quad lane
          float rin = 1.f / fmaxf(sqrtf(ss), 1e-12f);
          cpn[base + l15] = v0 * rin;
          cpn[base + 16 + l15] = v1 * rin;
        } else {
          cval[base + l15] = v0;
          cval[base + 16 + l15] = v1;
        }
      }
    }
  }
}

// ---------------------------------------------------------------------------
// sim: per block one (n,f), 64 l-rows; centers as TWO tiles of 128 looped
// in-block. 128 threads, thread 8 rows {4tr+i, 32+4tr+i} x 8 centers
// {4tc+c, 64+4tc+c} per tile. G=4 k-batched LDS reads. X rows l2-normalized
// at staging. Argmax of a*sim+b folded across tiles in-thread, then 16-lane
// shfl_xor reduce (min-index tie). Gather c_value, scale by sigmoid(max),
// write dispatched IN PLACE over xn.                       (UNCHANGED)
// ---------------------------------------------------------------------------
__global__ __launch_bounds__(128) void sim_k(
    float* __restrict__ xn, const float* __restrict__ cpn,
    const float* __restrict__ cval, const float* __restrict__ alphap,
    const float* __restrict__ betap) {
  __shared__ float Xs[32 * ASTR];  //  8.7 KB (rows 0..63)
  __shared__ float Cs[32 * BSTR];  // 16.9 KB (128 centers per tile)
  int t = threadIdx.x;
  int tc = t & 15, tr = t >> 4;    // tr in [0,8)
  int lt = blockIdx.x & 63;
  int nf = blockIdx.x >> 6;        // 0..31
  int f = nf & 7, nI = nf >> 3;
  int l0 = lt * 64;
  const float* cp = cpn + (size_t)nf * Ss * SC;

  // stage x rows 64x32, l2-normalized (8-lane shfl per row)
  {
    int jq = t & 7, r0 = 4 * (t >> 3);  // rows r0..r0+3
    int ph = ((jq >> 1) & 3) << 2;
    float4 v[4];
    float ssq[4];
#pragma unroll
    for (int i = 0; i < 4; i++) {
      v[i] = *(const float4*)(xn + ((size_t)nI * Ll + l0 + r0 + i) * Cc + f * SC + 4 * jq);
      ssq[i] = v[i].x * v[i].x + v[i].y * v[i].y + v[i].z * v[i].z + v[i].w * v[i].w;
    }
#pragma unroll
    for (int m = 1; m <= 4; m <<= 1)
#pragma unroll
      for (int i = 0; i < 4; i++) ssq[i] += __shfl_xor(ssq[i], m, 64);
#pragma unroll
    for (int i = 0; i < 4; i++) {
      float rin = 1.f / fmaxf(sqrtf(ssq[i]), 1e-12f);
      v[i].x *= rin; v[i].y *= rin; v[i].z *= rin; v[i].w *= rin;
    }
#pragma unroll
    for (int q = 0; q < 4; q++) {
      float4 w;
      w.x = ((const float*)&v[0])[q]; w.y = ((const float*)&v[1])[q];
      w.z = ((const float*)&v[2])[q]; w.w = ((const float*)&v[3])[q];
      *(float4*)&Xs[(4 * jq + q) * ASTR + (r0 ^ ph)] = w;
    }
  }

  float a = alphap[0], bt = betap[0];
  float best[8];
  int bi[8];
#pragma unroll
  for (int i = 0; i < 8; i++) { best[i] = -3.0e38f; bi[i] = 0; }

#pragma unroll 1
  for (int st = 0; st < 2; st++) {
    if (st) __syncthreads();  // previous tile's reads complete
    // stage 128 centers x 32 k (2 reg-transposed 4x4 blocks per thread)
#pragma unroll
    for (int it = 0; it < 2; it++) {
      int idx = t + 128 * it;
      int jq = idx & 7, c0 = 4 * (idx >> 3);  // c0 in {0..124}
      int ph = ((jq >> 1) & 3) << 2;
      float4 v[4];
#pragma unroll
      for (int i = 0; i < 4; i++)
        v[i] = *(const float4*)(cp + (size_t)(st * 128 + c0 + i) * SC + 4 * jq);
#pragma unroll
      for (int q = 0; q < 4; q++) {
        float4 w;
        w.x = ((const float*)&v[0])[q]; w.y = ((const float*)&v[1])[q];
        w.z = ((const float*)&v[2])[q]; w.w = ((const float*)&v[3])[q];
        *(float4*)&Cs[(4 * jq + q) * BSTR + (c0 ^ ph)] = w;
      }
    }
    __syncthreads();

    float acc[8][8];
#pragma unroll
    for (int i = 0; i < 8; i++)
#pragma unroll
      for (int c = 0; c < 8; c++) acc[i][c] = 0.f;

    int ia0 = 4 * tr, ib0 = 4 * tc;
#pragma unroll 1
    for (int kb = 0; kb < 32; kb += 4) {
      int ph = PHI(kb);
      int ja = ia0 ^ ph, jb = ib0 ^ ph;
      float4 A0[4], A1[4], B0[4], B1[4];
#pragma unroll
      for (int u = 0; u < 4; u++) {
        const float* ab = &Xs[(kb + u) * ASTR];
        const float* bb = &Cs[(kb + u) * BSTR];
        A0[u] = *(const float4*)&ab[ja];
        A1[u] = *(const float4*)&ab[32 + ja];
        B0[u] = *(const float4*)&bb[jb];
        B1[u] = *(const float4*)&bb[64 + jb];
      }
#pragma unroll
      for (int u = 0; u < 4; u++) {
        const float* af0 = (const float*)&A0[u];
        const float* af1 = (const float*)&A1[u];
        const float* bf0 = (const float*)&B0[u];
        const float* bf1 = (const float*)&B1[u];
#pragma unroll
        for (int i = 0; i < 4; i++) {
#pragma unroll
          for (int c = 0; c < 4; c++) {
            acc[i][c]         = fmaf(af0[i], bf0[c], acc[i][c]);
            acc[i][c + 4]     = fmaf(af0[i], bf1[c], acc[i][c + 4]);
            acc[i + 4][c]     = fmaf(af1[i], bf0[c], acc[i + 4][c]);
            acc[i + 4][c + 4] = fmaf(af1[i], bf1[c], acc[i + 4][c + 4]);
          }
        }
      }
    }

    // fold argmax (in-thread s strictly increasing across c and tiles)
#pragma unroll
    for (int i = 0; i < 8; i++) {
#pragma unroll
      for (int c = 0; c < 8; c++) {
        float tv = fmaf(a, acc[i][c], bt);
        int s = st * 128 + ((c < 4) ? (4 * tc + c) : (64 + 4 * tc + (c - 4)));
        if (tv > best[i]) { best[i] = tv; bi[i] = s; }
      }
    }
  }

#pragma unroll
  for (int i = 0; i < 8; i++) {
    int row = (i < 4) ? (4 * tr + i) : (32 + 4 * tr + (i - 4));
    float bv = best[i];
    int ix = bi[i];
#pragma unroll
    for (int m = 1; m <= 8; m <<= 1) {  // reduce across the 16 tc-lanes
      float ov = __shfl_xor(bv, m, 64);
      int oi = __shfl_xor(ix, m, 64);
      if (ov > bv || (ov == bv && oi < ix)) { bv = ov; ix = oi; }
    }
    float mv = 1.f / (1.f + expf(-bv));
    const float* cvp = cval + ((size_t)nf * Ss + ix) * SC;
    float* orow = xn + ((size_t)nI * Ll + l0 + row) * Cc + f * SC;
    orow[tc] = cvp[tc] * mv;
    orow[tc + 16] = cvp[tc + 16] * mv;
  }
}

// ---------------------------------------------------------------------------
// out = dispatched @ Wm^T + bm via bf16 MFMA, NO LDS.        (UNCHANGED)
// ---------------------------------------------------------------------------
__global__ __launch_bounds__(256) void out_mfma_k(
    const float* __restrict__ xn, const float* __restrict__ Wm,
    const float* __restrict__ bm, float* __restrict__ out) {
  int t = threadIdx.x;
  int wave = t >> 6, lane = t & 63;
  int quad = lane >> 4, l15 = lane & 15;
  size_t m0 = (size_t)(blockIdx.x >> 1) * 128 + (wave & 1) * 64;
  int n0 = (blockIdx.x & 1) * 128 + (wave >> 1) * 64;

  f32x4 acc[4][4];
#pragma unroll
  for (int ni = 0; ni < 4; ni++) {
    float bv = bm[n0 + ni * 16 + l15];
    f32x4 ci = {bv, bv, bv, bv};
#pragma unroll
    for (int mi = 0; mi < 4; mi++) acc[mi][ni] = ci;
  }

  for (int kt = 0; kt < 8; kt++) {
    int k0 = kt * 32 + quad * 8;
    short8 Af[4], Bf[4];
#pragma unroll
    for (int mi = 0; mi < 4; mi++) {
      const float* p = xn + (m0 + mi * 16 + l15) * Cc + k0;
      float4 lo = *(const float4*)p;
      float4 hi = *(const float4*)(p + 4);
      short8 fr;
      fr[0] = (short)f2bf(lo.x); fr[1] = (short)f2bf(lo.y);
      fr[2] = (short)f2bf(lo.z); fr[3] = (short)f2bf(lo.w);
      fr[4] = (short)f2bf(hi.x); fr[5] = (short)f2bf(hi.y);
      fr[6] = (short)f2bf(hi.z); fr[7] = (short)f2bf(hi.w);
      Af[mi] = fr;
    }
#pragma unroll
    for (int ni = 0; ni < 4; ni++) {
      const float* p = Wm + (size_t)(n0 + ni * 16 + l15) * Cc + k0;
      float4 lo = *(const float4*)p;
      float4 hi = *(const float4*)(p + 4);
      short8 fr;
      fr[0] = (short)f2bf(lo.x); fr[1] = (short)f2bf(lo.y);
      fr[2] = (short)f2bf(lo.z); fr[3] = (short)f2bf(lo.w);
      fr[4] = (short)f2bf(hi.x); fr[5] = (short)f2bf(hi.y);
      fr[6] = (short)f2bf(hi.z); fr[7] = (short)f2bf(hi.w);
      Bf[ni] = fr;
    }
#pragma unroll
    for (int mi = 0; mi < 4; mi++)
#pragma unroll
      for (int ni = 0; ni < 4; ni++)
        acc[mi][ni] = __builtin_amdgcn_mfma_f32_16x16x32_bf16(
            Af[mi], Bf[ni], acc[mi][ni], 0, 0, 0);
  }

#pragma unroll
  for (int mi = 0; mi < 4; mi++) {
#pragma unroll
    for (int reg = 0; reg < 4; reg++) {
      size_t row = m0 + mi * 16 + quad * 4 + reg;
      float* orow = out + row * Cc + n0;
#pragma unroll
      for (int ni = 0; ni < 4; ni++)
        orow[ni * 16 + l15] = acc[mi][ni][reg];
    }
  }
}

// ---------------------------------------------------------------------------
extern "C" void kernel_launch(void* const* d_in, const int* in_sizes, int n_in,
                              void* d_out, int out_size, void* d_ws, size_t ws_size,
                              hipStream_t stream) {
  const float* x0      = (const float*)d_in[0];
  const float* center1 = (const float*)d_in[1];
  const float* W0      = (const float*)d_in[2];
  const float* b0      = (const float*)d_in[3];
  const float* W1      = (const float*)d_in[4];
  const float* b1      = (const float*)d_in[5];
  const float* Wm      = (const float*)d_in[6];
  const float* bm      = (const float*)d_in[7];
  const float* alpha   = (const float*)d_in[8];
  const float* beta    = (const float*)d_in[9];
  float* out = (float*)d_out;
  float* ws  = (float*)d_ws;

  float* xn   = ws;                              // 16 MB: x0p, then dispatched in-place
  float* cpn  = xn + (size_t)Nn * Ll * Cc;       // 1 MB
  float* cval = cpn + (size_t)Nn * FC * Ss * SC; // 1 MB  (total 18 MB)

  proj_mfma_k<<<dim3(576), dim3(256), 0, stream>>>(
      x0, W0, b0, center1, W1, b1, xn, cpn, cval);
  sim_k<<<dim3(32 * 64), dim3(128), 0, stream>>>(xn, cpn, cval, alpha, beta);
  out_mfma_k<<<dim3(256), dim3(256), 0, stream>>>(xn, Wm, bm, out);
}

// Round 4
// 161.834 us; speedup vs baseline: 1.1781x; 1.1229x over previous
//
#include <hip/hip_runtime.h>
#include <math.h>

// Problem constants (fixed by setup_inputs)
#define Nn 4
#define Ll 4096
#define Ss 256
#define Cc 256
#define FC 8
#define SC 32

typedef __attribute__((ext_vector_type(8))) short short8;     // 8 bf16 frag
typedef __attribute__((ext_vector_type(8))) _Float16 half8;   // 8 f16 frag
typedef __attribute__((ext_vector_type(4))) float f32x4;      // MFMA acc

__device__ __forceinline__ unsigned short f2bf(float x) {   // RTNE f32->bf16
  unsigned int u = __float_as_uint(x);
  return (unsigned short)((u + 0x7FFFu + ((u >> 16) & 1u)) >> 16);
}

// ---------------------------------------------------------------------------
// fp32-accurate f16-split GEMM on matrix cores (verified absmax 0.0078).
// x = hi + lo/2048 + eps, |eps| <= 2^-22 |x|.
// ---------------------------------------------------------------------------
__device__ __forceinline__ void split8v(float4 a, float4 b,
                                        half8& hi, half8& lo) {
  float v[8] = {a.x, a.y, a.z, a.w, b.x, b.y, b.z, b.w};
#pragma unroll
  for (int i = 0; i < 8; i++) {
    float x = v[i];
    _Float16 h = (_Float16)x;          // v_cvt_f16_f32 (RTNE)
    float r = (x - (float)h) * 2048.f; // exact residual, pre-scaled
    hi[i] = h;
    lo[i] = (_Float16)r;
  }
}

#define PROJ_LOAD(Abuf, Bbuf, KOFF)                                     \
  {                                                                     \
    _Pragma("unroll")                                                   \
    for (int mi = 0; mi < 4; mi++) {                                    \
      const float* p = Ab + (size_t)mi * 16 * Cc + (KOFF);              \
      Abuf[mi][0] = *(const float4*)p;                                  \
      Abuf[mi][1] = *(const float4*)(p + 4);                            \
    }                                                                   \
    _Pragma("unroll")                                                   \
    for (int ni = 0; ni < 2; ni++) {                                    \
      const float* p = Bb + (size_t)ni * 16 * Cc + (KOFF);              \
      Bbuf[ni][0] = *(const float4*)p;                                  \
      Bbuf[ni][1] = *(const float4*)(p + 4);                            \
    }                                                                   \
  }

#define PROJ_COMPUTE(Abuf, Bbuf)                                        \
  {                                                                     \
    half8 Bh[2], Bl[2];                                                 \
    _Pragma("unroll")                                                   \
    for (int ni = 0; ni < 2; ni++)                                      \
      split8v(Bbuf[ni][0], Bbuf[ni][1], Bh[ni], Bl[ni]);                \
    _Pragma("unroll")                                                   \
    for (int mi = 0; mi < 4; mi++) {                                    \
      half8 Ah, Al;                                                     \
      split8v(Abuf[mi][0], Abuf[mi][1], Ah, Al);                        \
      _Pragma("unroll")                                                 \
      for (int ni = 0; ni < 2; ni++) {                                  \
        acc1[mi][ni] = __builtin_amdgcn_mfma_f32_16x16x32_f16(          \
            Ah, Bh[ni], acc1[mi][ni], 0, 0, 0);                         \
        acc2[mi][ni] = __builtin_amdgcn_mfma_f32_16x16x32_f16(          \
            Ah, Bl[ni], acc2[mi][ni], 0, 0, 0);                         \
        acc2[mi][ni] = __builtin_amdgcn_mfma_f32_16x16x32_f16(          \
            Al, Bh[ni], acc2[mi][ni], 0, 0, 0);                         \
      }                                                                 \
    }                                                                   \
  }

// 64x32 per-wave tile, K=256, no LDS. Software-pipelined: prefetch kt+1
// raw float4s (independent loads) while kt is split+MFMA'd.   (UNCHANGED)
__device__ __forceinline__ void mfma_core_f32(
    const float* __restrict__ A, const float* __restrict__ B,
    const float* __restrict__ bias, size_t m0w, int n0w, int lane,
    f32x4 acc1[4][2], f32x4 acc2[4][2]) {
  int quad = lane >> 4, l15 = lane & 15;
#pragma unroll
  for (int ni = 0; ni < 2; ni++) {
    float bv = bias[n0w + ni * 16 + l15];
    f32x4 ci = {bv, bv, bv, bv};
    f32x4 zz = {0.f, 0.f, 0.f, 0.f};
#pragma unroll
    for (int mi = 0; mi < 4; mi++) { acc1[mi][ni] = ci; acc2[mi][ni] = zz; }
  }
  const float* Ab = A + (m0w + l15) * Cc + quad * 8;
  const float* Bb = B + (size_t)(n0w + l15) * Cc + quad * 8;

  float4 cA[4][2], cB[2][2], nA[4][2], nB[2][2];
  PROJ_LOAD(cA, cB, 0);
#pragma unroll 1
  for (int kt = 0; kt < 8; kt += 2) {
    PROJ_LOAD(nA, nB, (kt + 1) * 32);       // prefetch odd step
    PROJ_COMPUTE(cA, cB);
    if (kt < 6) PROJ_LOAD(cA, cB, (kt + 2) * 32);  // prefetch next even
    PROJ_COMPUTE(nA, nB);
  }
}

// ---------------------------------------------------------------------------
// Fused projections (UNCHANGED from round-3 measured-good version).
// ---------------------------------------------------------------------------
__global__ __launch_bounds__(256, 2) void proj_mfma_k(
    const float* __restrict__ x0, const float* __restrict__ W0,
    const float* __restrict__ b0, const float* __restrict__ center1,
    const float* __restrict__ W1, const float* __restrict__ b1,
    float* __restrict__ xn, float* __restrict__ cpn, float* __restrict__ cval) {
  int t = threadIdx.x;
  int wave = t >> 6, lane = t & 63;
  int quad = lane >> 4, l15 = lane & 15;
  int b = blockIdx.x;
  f32x4 acc1[4][2], acc2[4][2];

  if (b < 512) {
    int r = (b & 7) + 8 * ((b >> 3) & 15);  // row-tile 0..127 (XCD-local)
    int cb = b >> 7;                        // col-block 0..3
    size_t m0 = (size_t)r * 128 + (size_t)(wave & 1) * 64;
    int n0 = cb * 64 + (wave >> 1) * 32;
    mfma_core_f32(x0, W0, b0, m0, n0, lane, acc1, acc2);
#pragma unroll
    for (int mi = 0; mi < 4; mi++) {
#pragma unroll
      for (int reg = 0; reg < 4; reg++) {
        size_t row = m0 + mi * 16 + quad * 4 + reg;
        float* orow = xn + row * Cc + n0;
#pragma unroll
        for (int ni = 0; ni < 2; ni++)
          orow[ni * 16 + l15] =
              acc1[mi][ni][reg] + acc2[mi][ni][reg] * (1.f / 2048.f);
      }
    }
  } else {
    int b2 = b - 512;
    size_t m0 = (size_t)(b2 >> 3) * 128 + (size_t)(wave & 1) * 64;
    int n0 = (b2 & 7) * 64 + (wave >> 1) * 32;   // N=512
    mfma_core_f32(center1, W1, b1, m0, n0, lane, acc1, acc2);
    int f = n0 >> 6;                   // fiber
    bool point = (n0 & 32) == 0;       // cols (n0&63)+0..31: point iff ==0
#pragma unroll
    for (int mi = 0; mi < 4; mi++) {
#pragma unroll
      for (int reg = 0; reg < 4; reg++) {
        int row = (int)m0 + mi * 16 + quad * 4 + reg;  // 0..1023 = nI*256+s
        int nI = row >> 8, s = row & 255;
        float v0 = acc1[mi][0][reg] + acc2[mi][0][reg] * (1.f / 2048.f);
        float v1 = acc1[mi][1][reg] + acc2[mi][1][reg] * (1.f / 2048.f);
        size_t base = (((size_t)nI * FC + f) * Ss + s) * SC;
        if (point) {
          float ss = v0 * v0 + v1 * v1;     // 2 elems/lane x 16 lanes = 32
          ss += __shfl_xor(ss, 1, 64);
          ss += __shfl_xor(ss, 2, 64);
          ss += __shfl_xor(ss, 4, 64);
          ss += __shfl_xor(ss, 8, 64);      // full row in every quad lane
          float rin = 1.f / fmaxf(sqrtf(ss), 1e-12f);
          cpn[base + l15] = v0 * rin;
          cpn[base + 16 + l15] = v1 * rin;
        } else {
          cval[base + l15] = v0;
          cval[base + 16 + l15] = v1;
        }
      }
    }
  }
}

// ---------------------------------------------------------------------------
// ROUND-14: sim on matrix cores. Old sim_k was the top dispatch (52us,
// MfmaUtil 0, VALUBusy 45%, fp32-VALU floor 13.7us). K=32 fits ONE
// 16x16x32_f16 MFMA; f16-split on l2-NORMALIZED inputs (|elem|~0.18) has
// ~1e-7 abs error -- below the fp32 fma-chain error of the previously
// passing kernel, so argmax ordering risk is unchanged.
// Block: one (nf, 64-l-row tile); 4 waves x 16 l-rows; all 256 centers.
// Centers split ONCE per block into LDS [quad][256] half8 planes (32KB,
// consecutive-lane 16B stride = conflict-free). Per wave: 16 frags x
// (2 ds_read_b128 + 3 MFMA) + in-reg argmax fold (s=16j+l15 increasing ->
// first-max tie-break preserved; cross-lane min-index on ties).
// ---------------------------------------------------------------------------
__global__ __launch_bounds__(256) void sim_k(
    float* __restrict__ xn, const float* __restrict__ cpn,
    const float* __restrict__ cval, const float* __restrict__ alphap,
    const float* __restrict__ betap) {
  __shared__ half8 BhS[4][256];   // [k-quad][s] hi planes, 16 KB
  __shared__ half8 BlS[4][256];   // lo planes, 16 KB
  int t = threadIdx.x;
  int wave = t >> 6, lane = t & 63;
  int quad = lane >> 4, l15 = lane & 15;
  int lt = blockIdx.x & 63;
  int nf = blockIdx.x >> 6;        // 0..31
  int f = nf & 7, nI = nf >> 3;
  int l0 = lt * 64;
  const float* cp = cpn + (size_t)nf * Ss * SC;

  // ---- stage + split all 256 centers: thread t = center row s ----
  {
    int s = t;
    float4 va[8];
#pragma unroll
    for (int q8 = 0; q8 < 8; q8++)
      va[q8] = *(const float4*)(cp + (size_t)s * SC + q8 * 4);
#pragma unroll
    for (int q = 0; q < 4; q++) {
      half8 h, l;
      split8v(va[2 * q], va[2 * q + 1], h, l);
      BhS[q][s] = h;
      BlS[q][s] = l;
    }
  }

  // ---- A: load own row slice, l2-normalize, split ----
  // lane covers row l0+wave*16+l15, k = quad*8..+7
  half8 Ah, Al;
  {
    const float* xrow =
        xn + ((size_t)nI * Ll + l0 + wave * 16 + l15) * Cc + f * SC + quad * 8;
    float4 a0 = *(const float4*)xrow;
    float4 a1 = *(const float4*)(xrow + 4);
    float ssq = a0.x * a0.x + a0.y * a0.y + a0.z * a0.z + a0.w * a0.w +
                a1.x * a1.x + a1.y * a1.y + a1.z * a1.z + a1.w * a1.w;
    ssq += __shfl_xor(ssq, 16, 64);   // reduce across the 4 quads
    ssq += __shfl_xor(ssq, 32, 64);   // (lanes sharing l15)
    float rin = 1.f / fmaxf(sqrtf(ssq), 1e-12f);
    a0.x *= rin; a0.y *= rin; a0.z *= rin; a0.w *= rin;
    a1.x *= rin; a1.y *= rin; a1.z *= rin; a1.w *= rin;
    split8v(a0, a1, Ah, Al);
  }

  __syncthreads();   // center planes visible

  float a = alphap[0], bt = betap[0];
  float best[4];
  int bi[4];
#pragma unroll
  for (int r = 0; r < 4; r++) { best[r] = -3.0e38f; bi[r] = 0; }

  // ---- 16 s-fragments: 2 ds_read_b128 + 3 MFMA each ----
#pragma unroll
  for (int j = 0; j < 16; j++) {
    half8 bh = BhS[quad][j * 16 + l15];
    half8 bl = BlS[quad][j * 16 + l15];
    f32x4 z = {0.f, 0.f, 0.f, 0.f};
    f32x4 c1 = __builtin_amdgcn_mfma_f32_16x16x32_f16(Ah, bh, z, 0, 0, 0);
    f32x4 c2 = __builtin_amdgcn_mfma_f32_16x16x32_f16(Ah, bl, z, 0, 0, 0);
    c2 = __builtin_amdgcn_mfma_f32_16x16x32_f16(Al, bh, c2, 0, 0, 0);
    int s = j * 16 + l15;
#pragma unroll
    for (int r = 0; r < 4; r++) {
      float v = c1[r] + c2[r] * (1.f / 2048.f);
      float tv = fmaf(a, v, bt);
      if (tv > best[r]) { best[r] = tv; bi[r] = s; }
    }
  }

  // ---- cross-lane argmax (16 l15-lanes per quad), gather, write ----
#pragma unroll
  for (int r = 0; r < 4; r++) {
    float bv = best[r];
    int ix = bi[r];
#pragma unroll
    for (int m = 1; m <= 8; m <<= 1) {
      float ov = __shfl_xor(bv, m, 64);
      int oi = __shfl_xor(ix, m, 64);
      if (ov > bv || (ov == bv && oi < ix)) { bv = ov; ix = oi; }
    }
    float mv = 1.f / (1.f + expf(-bv));
    const float* cvp = cval + ((size_t)nf * Ss + ix) * SC;
    float* orow =
        xn + ((size_t)nI * Ll + l0 + wave * 16 + quad * 4 + r) * Cc + f * SC;
    orow[l15] = cvp[l15] * mv;
    orow[l15 + 16] = cvp[l15 + 16] * mv;
  }
}

// ---------------------------------------------------------------------------
// out = dispatched @ Wm^T + bm via bf16 MFMA, NO LDS.        (UNCHANGED)
// ---------------------------------------------------------------------------
__global__ __launch_bounds__(256) void out_mfma_k(
    const float* __restrict__ xn, const float* __restrict__ Wm,
    const float* __restrict__ bm, float* __restrict__ out) {
  int t = threadIdx.x;
  int wave = t >> 6, lane = t & 63;
  int quad = lane >> 4, l15 = lane & 15;
  size_t m0 = (size_t)(blockIdx.x >> 1) * 128 + (wave & 1) * 64;
  int n0 = (blockIdx.x & 1) * 128 + (wave >> 1) * 64;

  f32x4 acc[4][4];
#pragma unroll
  for (int ni = 0; ni < 4; ni++) {
    float bv = bm[n0 + ni * 16 + l15];
    f32x4 ci = {bv, bv, bv, bv};
#pragma unroll
    for (int mi = 0; mi < 4; mi++) acc[mi][ni] = ci;
  }

  for (int kt = 0; kt < 8; kt++) {
    int k0 = kt * 32 + quad * 8;
    short8 Af[4], Bf[4];
#pragma unroll
    for (int mi = 0; mi < 4; mi++) {
      const float* p = xn + (m0 + mi * 16 + l15) * Cc + k0;
      float4 lo = *(const float4*)p;
      float4 hi = *(const float4*)(p + 4);
      short8 fr;
      fr[0] = (short)f2bf(lo.x); fr[1] = (short)f2bf(lo.y);
      fr[2] = (short)f2bf(lo.z); fr[3] = (short)f2bf(lo.w);
      fr[4] = (short)f2bf(hi.x); fr[5] = (short)f2bf(hi.y);
      fr[6] = (short)f2bf(hi.z); fr[7] = (short)f2bf(hi.w);
      Af[mi] = fr;
    }
#pragma unroll
    for (int ni = 0; ni < 4; ni++) {
      const float* p = Wm + (size_t)(n0 + ni * 16 + l15) * Cc + k0;
      float4 lo = *(const float4*)p;
      float4 hi = *(const float4*)(p + 4);
      short8 fr;
      fr[0] = (short)f2bf(lo.x); fr[1] = (short)f2bf(lo.y);
      fr[2] = (short)f2bf(lo.z); fr[3] = (short)f2bf(lo.w);
      fr[4] = (short)f2bf(hi.x); fr[5] = (short)f2bf(hi.y);
      fr[6] = (short)f2bf(hi.z); fr[7] = (short)f2bf(hi.w);
      Bf[ni] = fr;
    }
#pragma unroll
    for (int mi = 0; mi < 4; mi++)
#pragma unroll
      for (int ni = 0; ni < 4; ni++)
        acc[mi][ni] = __builtin_amdgcn_mfma_f32_16x16x32_bf16(
            Af[mi], Bf[ni], acc[mi][ni], 0, 0, 0);
  }

#pragma unroll
  for (int mi = 0; mi < 4; mi++) {
#pragma unroll
    for (int reg = 0; reg < 4; reg++) {
      size_t row = m0 + mi * 16 + quad * 4 + reg;
      float* orow = out + row * Cc + n0;
#pragma unroll
      for (int ni = 0; ni < 4; ni++)
        orow[ni * 16 + l15] = acc[mi][ni][reg];
    }
  }
}

// ---------------------------------------------------------------------------
extern "C" void kernel_launch(void* const* d_in, const int* in_sizes, int n_in,
                              void* d_out, int out_size, void* d_ws, size_t ws_size,
                              hipStream_t stream) {
  const float* x0      = (const float*)d_in[0];
  const float* center1 = (const float*)d_in[1];
  const float* W0      = (const float*)d_in[2];
  const float* b0      = (const float*)d_in[3];
  const float* W1      = (const float*)d_in[4];
  const float* b1      = (const float*)d_in[5];
  const float* Wm      = (const float*)d_in[6];
  const float* bm      = (const float*)d_in[7];
  const float* alpha   = (const float*)d_in[8];
  const float* beta    = (const float*)d_in[9];
  float* out = (float*)d_out;
  float* ws  = (float*)d_ws;

  float* xn   = ws;                              // 16 MB: x0p, then dispatched in-place
  float* cpn  = xn + (size_t)Nn * Ll * Cc;       // 1 MB
  float* cval = cpn + (size_t)Nn * FC * Ss * SC; // 1 MB  (total 18 MB)

  proj_mfma_k<<<dim3(576), dim3(256), 0, stream>>>(
      x0, W0, b0, center1, W1, b1, xn, cpn, cval);
  sim_k<<<dim3(32 * 64), dim3(256), 0, stream>>>(xn, cpn, cval, alpha, beta);
  out_mfma_k<<<dim3(256), dim3(256), 0, stream>>>(xn, Wm, bm, out);
}

// Round 6
// 159.425 us; speedup vs baseline: 1.1959x; 1.0151x over previous
//
#include <hip/hip_runtime.h>
#include <math.h>

// Problem constants (fixed by setup_inputs)
#define Nn 4
#define Ll 4096
#define Ss 256
#define Cc 256
#define FC 8
#define SC 32

typedef __attribute__((ext_vector_type(8))) short short8;     // 8 bf16 frag
typedef __attribute__((ext_vector_type(8))) _Float16 half8;   // 8 f16 frag
typedef __attribute__((ext_vector_type(4))) float f32x4;      // MFMA acc

__device__ __forceinline__ unsigned short f2bf(float x) {   // RTNE f32->bf16
  unsigned int u = __float_as_uint(x);
  return (unsigned short)((u + 0x7FFFu + ((u >> 16) & 1u)) >> 16);
}

// ---------------------------------------------------------------------------
// fp32-accurate f16-split GEMM on matrix cores (verified absmax 0.0078).
// x = hi + lo/2048 + eps, |eps| <= 2^-22 |x|.
// ROUND-15 (resubmitted round-16; round-15 bench died in GPU acquisition):
// proj still latency-bound (Mfma 5.8%, VALU 13.5%, occ 12%).
// Diagnosis: 64x32 wave tile needs ~190 VGPR for the 2-deep prefetch but
// compiled at 100 -> allocator recycled buffers -> loads re-serialized
// (45us / 2.25 blk/CU = 20us/blk ~ 96 un-overlapped load latencies).
// Fix: 32x32 wave tile. acc 64->32, buffers 96->64 VGPR (~125 total,
// fits the 128-VGPR tier via __launch_bounds__(256,4)), and wave count
// doubles to 4608 (~4.5/SIMD) for TLP. XCD mapping: rt=b&255, cb=b>>8
// keeps the 4 col-tiles of a row-tile on one XCD (b mod 8 invariant).
// ---------------------------------------------------------------------------
__device__ __forceinline__ void split8v(float4 a, float4 b,
                                        half8& hi, half8& lo) {
  float v[8] = {a.x, a.y, a.z, a.w, b.x, b.y, b.z, b.w};
#pragma unroll
  for (int i = 0; i < 8; i++) {
    float x = v[i];
    _Float16 h = (_Float16)x;          // v_cvt_f16_f32 (RTNE)
    float r = (x - (float)h) * 2048.f; // exact residual, pre-scaled
    hi[i] = h;
    lo[i] = (_Float16)r;
  }
}

#define LOAD32(Abuf, Bbuf, KOFF)                                        \
  {                                                                     \
    _Pragma("unroll")                                                   \
    for (int mi = 0; mi < 2; mi++) {                                    \
      const float* p = Ab + (size_t)mi * 16 * Cc + (KOFF);              \
      Abuf[mi][0] = *(const float4*)p;                                  \
      Abuf[mi][1] = *(const float4*)(p + 4);                            \
    }                                                                   \
    _Pragma("unroll")                                                   \
    for (int ni = 0; ni < 2; ni++) {                                    \
      const float* p = Bb + (size_t)ni * 16 * Cc + (KOFF);              \
      Bbuf[ni][0] = *(const float4*)p;                                  \
      Bbuf[ni][1] = *(const float4*)(p + 4);                            \
    }                                                                   \
  }

// B split per-ni inside the loop keeps transient half8 pressure low
// (peak live: 64 buf + 32 acc + 16 A-split + 8 B-split + addr ~ 125).
#define COMP32(Abuf, Bbuf)                                              \
  {                                                                     \
    half8 Ah[2], Al[2];                                                 \
    _Pragma("unroll")                                                   \
    for (int mi = 0; mi < 2; mi++)                                      \
      split8v(Abuf[mi][0], Abuf[mi][1], Ah[mi], Al[mi]);                \
    _Pragma("unroll")                                                   \
    for (int ni = 0; ni < 2; ni++) {                                    \
      half8 Bh, Bl;                                                     \
      split8v(Bbuf[ni][0], Bbuf[ni][1], Bh, Bl);                        \
      _Pragma("unroll")                                                 \
      for (int mi = 0; mi < 2; mi++) {                                  \
        acc1[mi][ni] = __builtin_amdgcn_mfma_f32_16x16x32_f16(          \
            Ah[mi], Bh, acc1[mi][ni], 0, 0, 0);                         \
        acc2[mi][ni] = __builtin_amdgcn_mfma_f32_16x16x32_f16(          \
            Ah[mi], Bl, acc2[mi][ni], 0, 0, 0);                         \
        acc2[mi][ni] = __builtin_amdgcn_mfma_f32_16x16x32_f16(          \
            Al[mi], Bh, acc2[mi][ni], 0, 0, 0);                         \
      }                                                                 \
    }                                                                   \
  }

// 32x32 per-wave tile, K=256, no LDS, 2-deep register prefetch.
__device__ __forceinline__ void mfma_core32(
    const float* __restrict__ A, const float* __restrict__ B,
    const float* __restrict__ bias, size_t m0w, int n0w, int lane,
    f32x4 acc1[2][2], f32x4 acc2[2][2]) {
  int quad = lane >> 4, l15 = lane & 15;
#pragma unroll
  for (int ni = 0; ni < 2; ni++) {
    float bv = bias[n0w + ni * 16 + l15];
    f32x4 ci = {bv, bv, bv, bv};
    f32x4 zz = {0.f, 0.f, 0.f, 0.f};
#pragma unroll
    for (int mi = 0; mi < 2; mi++) { acc1[mi][ni] = ci; acc2[mi][ni] = zz; }
  }
  const float* Ab = A + (m0w + l15) * Cc + quad * 8;
  const float* Bb = B + (size_t)(n0w + l15) * Cc + quad * 8;

  float4 cA[2][2], cB[2][2], nA[2][2], nB[2][2];
  LOAD32(cA, cB, 0);
#pragma unroll 1
  for (int kt = 0; kt < 8; kt += 2) {
    LOAD32(nA, nB, (kt + 1) * 32);                 // prefetch odd step
    COMP32(cA, cB);
    if (kt < 6) LOAD32(cA, cB, (kt + 2) * 32);     // prefetch next even
    COMP32(nA, nB);
  }
}

// ---------------------------------------------------------------------------
// Fused projections. Blocks 0..1023: xn = x0 @ W0^T + b0 (M=16384, N=256,
// block tile 64x64, 4 waves of 32x32). rt = b&255, cb = b>>8: the 4
// col-tiles of a row-tile share b mod 8 -> same XCD; 2MB/XCD A-set in L2.
// Blocks 1024..1151: c1 = center1 @ W1^T + b1 (M=1024, N=512) with split/
// l2norm epilogue -> cpn (normalized point half), cval (raw value half).
// A 32-col wave tile lies entirely in one half (n0 multiple of 32).
// ---------------------------------------------------------------------------
__global__ __launch_bounds__(256, 4) void proj_mfma_k(
    const float* __restrict__ x0, const float* __restrict__ W0,
    const float* __restrict__ b0, const float* __restrict__ center1,
    const float* __restrict__ W1, const float* __restrict__ b1,
    float* __restrict__ xn, float* __restrict__ cpn, float* __restrict__ cval) {
  int t = threadIdx.x;
  int wave = t >> 6, lane = t & 63;
  int quad = lane >> 4, l15 = lane & 15;
  int b = blockIdx.x;
  f32x4 acc1[2][2], acc2[2][2];

  if (b < 1024) {
    int rt = b & 255;                       // row-tile (64 rows)
    int cb = b >> 8;                        // col-tile 0..3
    size_t m0 = (size_t)rt * 64 + (size_t)(wave & 1) * 32;
    int n0 = cb * 64 + (wave >> 1) * 32;
    mfma_core32(x0, W0, b0, m0, n0, lane, acc1, acc2);
#pragma unroll
    for (int mi = 0; mi < 2; mi++) {
#pragma unroll
      for (int reg = 0; reg < 4; reg++) {
        size_t row = m0 + mi * 16 + quad * 4 + reg;
        float* orow = xn + row * Cc + n0;
#pragma unroll
        for (int ni = 0; ni < 2; ni++)
          orow[ni * 16 + l15] =
              acc1[mi][ni][reg] + acc2[mi][ni][reg] * (1.f / 2048.f);
      }
    }
  } else {
    int b2 = b - 1024;                      // 0..127
    size_t m0 = (size_t)(b2 >> 3) * 64 + (size_t)(wave & 1) * 32;
    int n0 = (b2 & 7) * 64 + (wave >> 1) * 32;   // N=512
    mfma_core32(center1, W1, b1, m0, n0, lane, acc1, acc2);
    int f = n0 >> 6;                   // fiber
    bool point = (n0 & 32) == 0;       // cols (n0&63)+0..31: point iff ==0
#pragma unroll
    for (int mi = 0; mi < 2; mi++) {
#pragma unroll
      for (int reg = 0; reg < 4; reg++) {
        int row = (int)m0 + mi * 16 + quad * 4 + reg;  // 0..1023 = nI*256+s
        int nI = row >> 8, s = row & 255;
        float v0 = acc1[mi][0][reg] + acc2[mi][0][reg] * (1.f / 2048.f);
        float v1 = acc1[mi][1][reg] + acc2[mi][1][reg] * (1.f / 2048.f);
        size_t base = (((size_t)nI * FC + f) * Ss + s) * SC;
        if (point) {
          float ss = v0 * v0 + v1 * v1;     // 2 elems/lane x 16 lanes = 32
          ss += __shfl_xor(ss, 1, 64);
          ss += __shfl_xor(ss, 2, 64);
          ss += __shfl_xor(ss, 4, 64);
          ss += __shfl_xor(ss, 8, 64);      // full row in every quad lane
          float rin = 1.f / fmaxf(sqrtf(ss), 1e-12f);
          cpn[base + l15] = v0 * rin;
          cpn[base + 16 + l15] = v1 * rin;
        } else {
          cval[base + l15] = v0;
          cval[base + 16 + l15] = v1;
        }
      }
    }
  }
}

// ---------------------------------------------------------------------------
// sim on matrix cores (round-14, measured-good; UNCHANGED).
// Block: one (nf, 64-l-row tile); 4 waves x 16 l-rows; all 256 centers.
// Centers split ONCE per block into LDS [quad][256] half8 planes (32KB).
// ---------------------------------------------------------------------------
__global__ __launch_bounds__(256) void sim_k(
    float* __restrict__ xn, const float* __restrict__ cpn,
    const float* __restrict__ cval, const float* __restrict__ alphap,
    const float* __restrict__ betap) {
  __shared__ half8 BhS[4][256];   // [k-quad][s] hi planes, 16 KB
  __shared__ half8 BlS[4][256];   // lo planes, 16 KB
  int t = threadIdx.x;
  int wave = t >> 6, lane = t & 63;
  int quad = lane >> 4, l15 = lane & 15;
  int lt = blockIdx.x & 63;
  int nf = blockIdx.x >> 6;        // 0..31
  int f = nf & 7, nI = nf >> 3;
  int l0 = lt * 64;
  const float* cp = cpn + (size_t)nf * Ss * SC;

  // ---- stage + split all 256 centers: thread t = center row s ----
  {
    int s = t;
    float4 va[8];
#pragma unroll
    for (int q8 = 0; q8 < 8; q8++)
      va[q8] = *(const float4*)(cp + (size_t)s * SC + q8 * 4);
#pragma unroll
    for (int q = 0; q < 4; q++) {
      half8 h, l;
      split8v(va[2 * q], va[2 * q + 1], h, l);
      BhS[q][s] = h;
      BlS[q][s] = l;
    }
  }

  // ---- A: load own row slice, l2-normalize, split ----
  half8 Ah, Al;
  {
    const float* xrow =
        xn + ((size_t)nI * Ll + l0 + wave * 16 + l15) * Cc + f * SC + quad * 8;
    float4 a0 = *(const float4*)xrow;
    float4 a1 = *(const float4*)(xrow + 4);
    float ssq = a0.x * a0.x + a0.y * a0.y + a0.z * a0.z + a0.w * a0.w +
                a1.x * a1.x + a1.y * a1.y + a1.z * a1.z + a1.w * a1.w;
    ssq += __shfl_xor(ssq, 16, 64);   // reduce across the 4 quads
    ssq += __shfl_xor(ssq, 32, 64);   // (lanes sharing l15)
    float rin = 1.f / fmaxf(sqrtf(ssq), 1e-12f);
    a0.x *= rin; a0.y *= rin; a0.z *= rin; a0.w *= rin;
    a1.x *= rin; a1.y *= rin; a1.z *= rin; a1.w *= rin;
    split8v(a0, a1, Ah, Al);
  }

  __syncthreads();   // center planes visible

  float a = alphap[0], bt = betap[0];
  float best[4];
  int bi[4];
#pragma unroll
  for (int r = 0; r < 4; r++) { best[r] = -3.0e38f; bi[r] = 0; }

  // ---- 16 s-fragments: 2 ds_read_b128 + 3 MFMA each ----
#pragma unroll
  for (int j = 0; j < 16; j++) {
    half8 bh = BhS[quad][j * 16 + l15];
    half8 bl = BlS[quad][j * 16 + l15];
    f32x4 z = {0.f, 0.f, 0.f, 0.f};
    f32x4 c1 = __builtin_amdgcn_mfma_f32_16x16x32_f16(Ah, bh, z, 0, 0, 0);
    f32x4 c2 = __builtin_amdgcn_mfma_f32_16x16x32_f16(Ah, bl, z, 0, 0, 0);
    c2 = __builtin_amdgcn_mfma_f32_16x16x32_f16(Al, bh, c2, 0, 0, 0);
    int s = j * 16 + l15;
#pragma unroll
    for (int r = 0; r < 4; r++) {
      float v = c1[r] + c2[r] * (1.f / 2048.f);
      float tv = fmaf(a, v, bt);
      if (tv > best[r]) { best[r] = tv; bi[r] = s; }
    }
  }

  // ---- cross-lane argmax (16 l15-lanes per quad), gather, write ----
#pragma unroll
  for (int r = 0; r < 4; r++) {
    float bv = best[r];
    int ix = bi[r];
#pragma unroll
    for (int m = 1; m <= 8; m <<= 1) {
      float ov = __shfl_xor(bv, m, 64);
      int oi = __shfl_xor(ix, m, 64);
      if (ov > bv || (ov == bv && oi < ix)) { bv = ov; ix = oi; }
    }
    float mv = 1.f / (1.f + expf(-bv));
    const float* cvp = cval + ((size_t)nf * Ss + ix) * SC;
    float* orow =
        xn + ((size_t)nI * Ll + l0 + wave * 16 + quad * 4 + r) * Cc + f * SC;
    orow[l15] = cvp[l15] * mv;
    orow[l15 + 16] = cvp[l15 + 16] * mv;
  }
}

// ---------------------------------------------------------------------------
// out = dispatched @ Wm^T + bm via bf16 MFMA, NO LDS.        (UNCHANGED)
// ---------------------------------------------------------------------------
__global__ __launch_bounds__(256) void out_mfma_k(
    const float* __restrict__ xn, const float* __restrict__ Wm,
    const float* __restrict__ bm, float* __restrict__ out) {
  int t = threadIdx.x;
  int wave = t >> 6, lane = t & 63;
  int quad = lane >> 4, l15 = lane & 15;
  size_t m0 = (size_t)(blockIdx.x >> 1) * 128 + (wave & 1) * 64;
  int n0 = (blockIdx.x & 1) * 128 + (wave >> 1) * 64;

  f32x4 acc[4][4];
#pragma unroll
  for (int ni = 0; ni < 4; ni++) {
    float bv = bm[n0 + ni * 16 + l15];
    f32x4 ci = {bv, bv, bv, bv};
#pragma unroll
    for (int mi = 0; mi < 4; mi++) acc[mi][ni] = ci;
  }

  for (int kt = 0; kt < 8; kt++) {
    int k0 = kt * 32 + quad * 8;
    short8 Af[4], Bf[4];
#pragma unroll
    for (int mi = 0; mi < 4; mi++) {
      const float* p = xn + (m0 + mi * 16 + l15) * Cc + k0;
      float4 lo = *(const float4*)p;
      float4 hi = *(const float4*)(p + 4);
      short8 fr;
      fr[0] = (short)f2bf(lo.x); fr[1] = (short)f2bf(lo.y);
      fr[2] = (short)f2bf(lo.z); fr[3] = (short)f2bf(lo.w);
      fr[4] = (short)f2bf(hi.x); fr[5] = (short)f2bf(hi.y);
      fr[6] = (short)f2bf(hi.z); fr[7] = (short)f2bf(hi.w);
      Af[mi] = fr;
    }
#pragma unroll
    for (int ni = 0; ni < 4; ni++) {
      const float* p = Wm + (size_t)(n0 + ni * 16 + l15) * Cc + k0;
      float4 lo = *(const float4*)p;
      float4 hi = *(const float4*)(p + 4);
      short8 fr;
      fr[0] = (short)f2bf(lo.x); fr[1] = (short)f2bf(lo.y);
      fr[2] = (short)f2bf(lo.z); fr[3] = (short)f2bf(lo.w);
      fr[4] = (short)f2bf(hi.x); fr[5] = (short)f2bf(hi.y);
      fr[6] = (short)f2bf(hi.z); fr[7] = (short)f2bf(hi.w);
      Bf[ni] = fr;
    }
#pragma unroll
    for (int mi = 0; mi < 4; mi++)
#pragma unroll
      for (int ni = 0; ni < 4; ni++)
        acc[mi][ni] = __builtin_amdgcn_mfma_f32_16x16x32_bf16(
            Af[mi], Bf[ni], acc[mi][ni], 0, 0, 0);
  }

#pragma unroll
  for (int mi = 0; mi < 4; mi++) {
#pragma unroll
    for (int reg = 0; reg < 4; reg++) {
      size_t row = m0 + mi * 16 + quad * 4 + reg;
      float* orow = out + row * Cc + n0;
#pragma unroll
      for (int ni = 0; ni < 4; ni++)
        orow[ni * 16 + l15] = acc[mi][ni][reg];
    }
  }
}

// ---------------------------------------------------------------------------
extern "C" void kernel_launch(void* const* d_in, const int* in_sizes, int n_in,
                              void* d_out, int out_size, void* d_ws, size_t ws_size,
                              hipStream_t stream) {
  const float* x0      = (const float*)d_in[0];
  const float* center1 = (const float*)d_in[1];
  const float* W0      = (const float*)d_in[2];
  const float* b0      = (const float*)d_in[3];
  const float* W1      = (const float*)d_in[4];
  const float* b1      = (const float*)d_in[5];
  const float* Wm      = (const float*)d_in[6];
  const float* bm      = (const float*)d_in[7];
  const float* alpha   = (const float*)d_in[8];
  const float* beta    = (const float*)d_in[9];
  float* out = (float*)d_out;
  float* ws  = (float*)d_ws;

  float* xn   = ws;                              // 16 MB: x0p, then dispatched in-place
  float* cpn  = xn + (size_t)Nn * Ll * Cc;       // 1 MB
  float* cval = cpn + (size_t)Nn * FC * Ss * SC; // 1 MB  (total 18 MB)

  proj_mfma_k<<<dim3(1152), dim3(256), 0, stream>>>(
      x0, W0, b0, center1, W1, b1, xn, cpn, cval);
  sim_k<<<dim3(32 * 64), dim3(256), 0, stream>>>(xn, cpn, cval, alpha, beta);
  out_mfma_k<<<dim3(256), dim3(256), 0, stream>>>(xn, Wm, bm, out);
}

// Round 8
// 149.457 us; speedup vs baseline: 1.2756x; 1.0667x over previous
//
#include <hip/hip_runtime.h>
#include <math.h>

// Problem constants (fixed by setup_inputs)
#define Nn 4
#define Ll 4096
#define Ss 256
#define Cc 256
#define FC 8
#define SC 32

typedef __attribute__((ext_vector_type(8))) short short8;     // 8 bf16 frag
typedef __attribute__((ext_vector_type(8))) _Float16 half8;   // 8 f16 frag
typedef __attribute__((ext_vector_type(4))) float f32x4;      // MFMA acc

__device__ __forceinline__ unsigned short f2bf(float x) {   // RTNE f32->bf16
  unsigned int u = __float_as_uint(x);
  return (unsigned short)((u + 0x7FFFu + ((u >> 16) & 1u)) >> 16);
}

// ---------------------------------------------------------------------------
// fp32-accurate f16-split on matrix cores (verified absmax 0.0078).
// x = hi + lo/2048 + eps, |eps| <= 2^-22 |x|.
// ROUND-17 (resubmitted round-18; round-17 bench died in GPU acquisition):
// register prefetch failed twice (VGPR clamped to 64, loads re-serialized,
// proj stuck at 45us, 806 GB/s = 13% of HBM). Switch to the guide-proven
// async pipeline: global_load_lds (width16) -> double-buffered LDS tiles,
// counted s_waitcnt vmcnt(6) so next tile's 6 loads stay in flight across
// the barrier (T3+T4). gload_lds writes LINEAR LDS, so the GLOBAL source
// is pre-swizzled (col16B = (l&7)^(l>>3)) and ds_reads use
// slot = q ^ (row&7)  -- else stride-128B rows = 16-way bank conflict.
// Block 128x64, BK=32, 4 waves x (64x32 tile): acc 64 VGPR, no reg buffers.
// ---------------------------------------------------------------------------
__device__ __forceinline__ void split8v(float4 a, float4 b,
                                        half8& hi, half8& lo) {
  float v[8] = {a.x, a.y, a.z, a.w, b.x, b.y, b.z, b.w};
#pragma unroll
  for (int i = 0; i < 8; i++) {
    float x = v[i];
    _Float16 h = (_Float16)x;          // v_cvt_f16_f32 (RTNE)
    float r = (x - (float)h) * 2048.f; // exact residual, pre-scaled
    hi[i] = h;
    lo[i] = (_Float16)r;
  }
}

// stage one 128x32 A-tile + 64x32 B-tile (fp32) into LDS, 6 gload/wave.
// chunk c = 8 rows; lane (lr=l>>3, l8=l&7) loads row 8c+lr, 16B-chunk
// (l8^lr) -> lands at linear LDS byte c*1024 + lane*16 (swizzled layout).
#define STAGE(Abuf, Bbuf, K0)                                               \
  {                                                                         \
    _Pragma("unroll")                                                       \
    for (int j = 0; j < 4; j++) {                                           \
      int c = wave * 4 + j;                                                 \
      const float* g = Ag + (m0blk + 8 * c + lr) * Cc + (K0) + scol;        \
      __builtin_amdgcn_global_load_lds(                                     \
          (const __attribute__((address_space(1))) void*)g,                 \
          (__attribute__((address_space(3))) void*)((Abuf) + c * 256),      \
          16, 0, 0);                                                        \
    }                                                                       \
    _Pragma("unroll")                                                       \
    for (int j = 0; j < 2; j++) {                                           \
      int c = wave * 2 + j;                                                 \
      const float* g =                                                      \
          Bg + (size_t)(n0blk + 8 * c + lr) * Cc + (K0) + scol;             \
      __builtin_amdgcn_global_load_lds(                                     \
          (const __attribute__((address_space(1))) void*)g,                 \
          (__attribute__((address_space(3))) void*)((Bbuf) + c * 256),      \
          16, 0, 0);                                                        \
    }                                                                       \
  }

// one K=32 step: 12 ds_read_b128 (XOR-swizzled) + 6 splits + 24 MFMA.
#define KSTEP(Ac, Bc)                                                       \
  {                                                                         \
    half8 Bh[2], Bl[2];                                                     \
    _Pragma("unroll")                                                       \
    for (int ni = 0; ni < 2; ni++) {                                        \
      int rw = bR0 + ni * 16 + l15;                                         \
      int rb = rw * 32, xs = rw & 7;                                        \
      float4 f0 = *(const float4*)&(Bc)[rb + (((quad * 2) ^ xs) << 2)];     \
      float4 f1 = *(const float4*)&(Bc)[rb + (((quad * 2 + 1) ^ xs) << 2)]; \
      split8v(f0, f1, Bh[ni], Bl[ni]);                                      \
    }                                                                       \
    _Pragma("unroll")                                                       \
    for (int mi = 0; mi < 4; mi++) {                                        \
      int rw = aR0 + mi * 16 + l15;                                         \
      int rb = rw * 32, xs = rw & 7;                                        \
      float4 f0 = *(const float4*)&(Ac)[rb + (((quad * 2) ^ xs) << 2)];     \
      float4 f1 = *(const float4*)&(Ac)[rb + (((quad * 2 + 1) ^ xs) << 2)]; \
      half8 Ah, Al;                                                         \
      split8v(f0, f1, Ah, Al);                                              \
      _Pragma("unroll")                                                     \
      for (int ni = 0; ni < 2; ni++) {                                      \
        acc1[mi][ni] = __builtin_amdgcn_mfma_f32_16x16x32_f16(              \
            Ah, Bh[ni], acc1[mi][ni], 0, 0, 0);                             \
        acc2[mi][ni] = __builtin_amdgcn_mfma_f32_16x16x32_f16(              \
            Ah, Bl[ni], acc2[mi][ni], 0, 0, 0);                             \
        acc2[mi][ni] = __builtin_amdgcn_mfma_f32_16x16x32_f16(              \
            Al, Bh[ni], acc2[mi][ni], 0, 0, 0);                             \
      }                                                                     \
    }                                                                       \
  }

// ---------------------------------------------------------------------------
// Fused projections. Blocks 0..511: xn = x0 @ W0^T + b0 (M=16384, N=256,
// 128 row-tiles x 4 col-tiles; rt=b&127 -> the 4 col-tiles of a row-tile
// share b mod 8 = same XCD, 2MB A-set in its L2). Blocks 512..575:
// c1 = center1 @ W1^T + b1 (M=1024, N=512) with split/l2norm epilogue ->
// cpn (normalized point half), cval (raw value half). Wave tile 64x32:
// n0w multiple of 32 -> entirely in one half.
// ---------------------------------------------------------------------------
__global__ __launch_bounds__(256) void proj_mfma_k(
    const float* __restrict__ x0, const float* __restrict__ W0,
    const float* __restrict__ b0, const float* __restrict__ center1,
    const float* __restrict__ W1, const float* __restrict__ b1,
    float* __restrict__ xn, float* __restrict__ cpn, float* __restrict__ cval) {
  __shared__ float As[2][128 * 32];   // 32 KB (2 x 16 KB)
  __shared__ float Bs[2][64 * 32];    // 16 KB (2 x  8 KB)
  int t = threadIdx.x;
  int wave = t >> 6, lane = t & 63;
  int quad = lane >> 4, l15 = lane & 15;
  int l8 = lane & 7, lr = lane >> 3;        // lr in [0,8)
  int scol = (l8 ^ lr) << 2;                // pre-swizzled source col (floats)
  int b = blockIdx.x;

  const float *Ag, *Bg, *bias;
  size_t m0blk;
  int n0blk;
  bool isX = (b < 512);
  if (isX) {
    int rt = b & 127, cb = b >> 7;
    m0blk = (size_t)rt * 128;
    n0blk = cb * 64;
    Ag = x0; Bg = W0; bias = b0;
  } else {
    int b2 = b - 512;
    m0blk = (size_t)(b2 >> 3) * 128;
    n0blk = (b2 & 7) * 64;                  // N=512
    Ag = center1; Bg = W1; bias = b1;
  }

  int n0w = n0blk + (wave >> 1) * 32;       // wave's output cols
  int aR0 = (wave & 1) * 64;                // wave's LDS A row base
  int bR0 = (wave >> 1) * 32;               // wave's LDS B row base

  f32x4 acc1[4][2], acc2[4][2];
#pragma unroll
  for (int ni = 0; ni < 2; ni++) {
    float bv = bias[n0w + ni * 16 + l15];
    f32x4 ci = {bv, bv, bv, bv};
    f32x4 zz = {0.f, 0.f, 0.f, 0.f};
#pragma unroll
    for (int mi = 0; mi < 4; mi++) { acc1[mi][ni] = ci; acc2[mi][ni] = zz; }
  }

  float* Ac = &As[0][0]; float* An = &As[1][0];
  float* Bc = &Bs[0][0]; float* Bn = &Bs[1][0];
  STAGE(Ac, Bc, 0);
#pragma unroll 1
  for (int kt = 0; kt < 8; kt++) {
    if (kt < 7) {
      STAGE(An, Bn, (kt + 1) * 32);
      asm volatile("s_waitcnt vmcnt(6)" ::: "memory");  // kt's 6 done; next 6 in flight
    } else {
      asm volatile("s_waitcnt vmcnt(0)" ::: "memory");
    }
    __builtin_amdgcn_sched_barrier(0);
    __syncthreads();                 // all waves' kt-tile in LDS
    KSTEP(Ac, Bc);
    __syncthreads();                 // done reading before overwrite
    float* tp;
    tp = Ac; Ac = An; An = tp;
    tp = Bc; Bc = Bn; Bn = tp;
  }

  if (isX) {
    size_t m0 = m0blk + aR0;
#pragma unroll
    for (int mi = 0; mi < 4; mi++) {
#pragma unroll
      for (int reg = 0; reg < 4; reg++) {
        size_t row = m0 + mi * 16 + quad * 4 + reg;
        float* orow = xn + row * Cc + n0w;
#pragma unroll
        for (int ni = 0; ni < 2; ni++)
          orow[ni * 16 + l15] =
              acc1[mi][ni][reg] + acc2[mi][ni][reg] * (1.f / 2048.f);
      }
    }
  } else {
    int f = n0w >> 6;                  // fiber
    bool point = (n0w & 32) == 0;      // cols (n0w&63)+0..31
    int m0 = (int)m0blk + aR0;
#pragma unroll
    for (int mi = 0; mi < 4; mi++) {
#pragma unroll
      for (int reg = 0; reg < 4; reg++) {
        int row = m0 + mi * 16 + quad * 4 + reg;   // 0..1023 = nI*256+s
        int nI = row >> 8, s = row & 255;
        float v0 = acc1[mi][0][reg] + acc2[mi][0][reg] * (1.f / 2048.f);
        float v1 = acc1[mi][1][reg] + acc2[mi][1][reg] * (1.f / 2048.f);
        size_t base = (((size_t)nI * FC + f) * Ss + s) * SC;
        if (point) {
          float ss = v0 * v0 + v1 * v1;    // 2 elems/lane x 16 lanes = 32
          ss += __shfl_xor(ss, 1, 64);
          ss += __shfl_xor(ss, 2, 64);
          ss += __shfl_xor(ss, 4, 64);
          ss += __shfl_xor(ss, 8, 64);     // full row norm in every lane
          float rin = 1.f / fmaxf(sqrtf(ss), 1e-12f);
          cpn[base + l15] = v0 * rin;
          cpn[base + 16 + l15] = v1 * rin;
        } else {
          cval[base + l15] = v0;
          cval[base + 16 + l15] = v1;
        }
      }
    }
  }
}

// ---------------------------------------------------------------------------
// sim on matrix cores (round-14, measured-good; UNCHANGED).
// Block: one (nf, 64-l-row tile); 4 waves x 16 l-rows; all 256 centers.
// Centers split ONCE per block into LDS [quad][256] half8 planes (32KB).
// ---------------------------------------------------------------------------
__global__ __launch_bounds__(256) void sim_k(
    float* __restrict__ xn, const float* __restrict__ cpn,
    const float* __restrict__ cval, const float* __restrict__ alphap,
    const float* __restrict__ betap) {
  __shared__ half8 BhS[4][256];   // [k-quad][s] hi planes, 16 KB
  __shared__ half8 BlS[4][256];   // lo planes, 16 KB
  int t = threadIdx.x;
  int wave = t >> 6, lane = t & 63;
  int quad = lane >> 4, l15 = lane & 15;
  int lt = blockIdx.x & 63;
  int nf = blockIdx.x >> 6;        // 0..31
  int f = nf & 7, nI = nf >> 3;
  int l0 = lt * 64;
  const float* cp = cpn + (size_t)nf * Ss * SC;

  // ---- stage + split all 256 centers: thread t = center row s ----
  {
    int s = t;
    float4 va[8];
#pragma unroll
    for (int q8 = 0; q8 < 8; q8++)
      va[q8] = *(const float4*)(cp + (size_t)s * SC + q8 * 4);
#pragma unroll
    for (int q = 0; q < 4; q++) {
      half8 h, l;
      split8v(va[2 * q], va[2 * q + 1], h, l);
      BhS[q][s] = h;
      BlS[q][s] = l;
    }
  }

  // ---- A: load own row slice, l2-normalize, split ----
  half8 Ah, Al;
  {
    const float* xrow =
        xn + ((size_t)nI * Ll + l0 + wave * 16 + l15) * Cc + f * SC + quad * 8;
    float4 a0 = *(const float4*)xrow;
    float4 a1 = *(const float4*)(xrow + 4);
    float ssq = a0.x * a0.x + a0.y * a0.y + a0.z * a0.z + a0.w * a0.w +
                a1.x * a1.x + a1.y * a1.y + a1.z * a1.z + a1.w * a1.w;
    ssq += __shfl_xor(ssq, 16, 64);   // reduce across the 4 quads
    ssq += __shfl_xor(ssq, 32, 64);   // (lanes sharing l15)
    float rin = 1.f / fmaxf(sqrtf(ssq), 1e-12f);
    a0.x *= rin; a0.y *= rin; a0.z *= rin; a0.w *= rin;
    a1.x *= rin; a1.y *= rin; a1.z *= rin; a1.w *= rin;
    split8v(a0, a1, Ah, Al);
  }

  __syncthreads();   // center planes visible

  float a = alphap[0], bt = betap[0];
  float best[4];
  int bi[4];
#pragma unroll
  for (int r = 0; r < 4; r++) { best[r] = -3.0e38f; bi[r] = 0; }

  // ---- 16 s-fragments: 2 ds_read_b128 + 3 MFMA each ----
#pragma unroll
  for (int j = 0; j < 16; j++) {
    half8 bh = BhS[quad][j * 16 + l15];
    half8 bl = BlS[quad][j * 16 + l15];
    f32x4 z = {0.f, 0.f, 0.f, 0.f};
    f32x4 c1 = __builtin_amdgcn_mfma_f32_16x16x32_f16(Ah, bh, z, 0, 0, 0);
    f32x4 c2 = __builtin_amdgcn_mfma_f32_16x16x32_f16(Ah, bl, z, 0, 0, 0);
    c2 = __builtin_amdgcn_mfma_f32_16x16x32_f16(Al, bh, c2, 0, 0, 0);
    int s = j * 16 + l15;
#pragma unroll
    for (int r = 0; r < 4; r++) {
      float v = c1[r] + c2[r] * (1.f / 2048.f);
      float tv = fmaf(a, v, bt);
      if (tv > best[r]) { best[r] = tv; bi[r] = s; }
    }
  }

  // ---- cross-lane argmax (16 l15-lanes per quad), gather, write ----
#pragma unroll
  for (int r = 0; r < 4; r++) {
    float bv = best[r];
    int ix = bi[r];
#pragma unroll
    for (int m = 1; m <= 8; m <<= 1) {
      float ov = __shfl_xor(bv, m, 64);
      int oi = __shfl_xor(ix, m, 64);
      if (ov > bv || (ov == bv && oi < ix)) { bv = ov; ix = oi; }
    }
    float mv = 1.f / (1.f + expf(-bv));
    const float* cvp = cval + ((size_t)nf * Ss + ix) * SC;
    float* orow =
        xn + ((size_t)nI * Ll + l0 + wave * 16 + quad * 4 + r) * Cc + f * SC;
    orow[l15] = cvp[l15] * mv;
    orow[l15 + 16] = cvp[l15 + 16] * mv;
  }
}

// ---------------------------------------------------------------------------
// out = dispatched @ Wm^T + bm via bf16 MFMA, NO LDS.        (UNCHANGED)
// ---------------------------------------------------------------------------
__global__ __launch_bounds__(256) void out_mfma_k(
    const float* __restrict__ xn, const float* __restrict__ Wm,
    const float* __restrict__ bm, float* __restrict__ out) {
  int t = threadIdx.x;
  int wave = t >> 6, lane = t & 63;
  int quad = lane >> 4, l15 = lane & 15;
  size_t m0 = (size_t)(blockIdx.x >> 1) * 128 + (wave & 1) * 64;
  int n0 = (blockIdx.x & 1) * 128 + (wave >> 1) * 64;

  f32x4 acc[4][4];
#pragma unroll
  for (int ni = 0; ni < 4; ni++) {
    float bv = bm[n0 + ni * 16 + l15];
    f32x4 ci = {bv, bv, bv, bv};
#pragma unroll
    for (int mi = 0; mi < 4; mi++) acc[mi][ni] = ci;
  }

  for (int kt = 0; kt < 8; kt++) {
    int k0 = kt * 32 + quad * 8;
    short8 Af[4], Bf[4];
#pragma unroll
    for (int mi = 0; mi < 4; mi++) {
      const float* p = xn + (m0 + mi * 16 + l15) * Cc + k0;
      float4 lo = *(const float4*)p;
      float4 hi = *(const float4*)(p + 4);
      short8 fr;
      fr[0] = (short)f2bf(lo.x); fr[1] = (short)f2bf(lo.y);
      fr[2] = (short)f2bf(lo.z); fr[3] = (short)f2bf(lo.w);
      fr[4] = (short)f2bf(hi.x); fr[5] = (short)f2bf(hi.y);
      fr[6] = (short)f2bf(hi.z); fr[7] = (short)f2bf(hi.w);
      Af[mi] = fr;
    }
#pragma unroll
    for (int ni = 0; ni < 4; ni++) {
      const float* p = Wm + (size_t)(n0 + ni * 16 + l15) * Cc + k0;
      float4 lo = *(const float4*)p;
      float4 hi = *(const float4*)(p + 4);
      short8 fr;
      fr[0] = (short)f2bf(lo.x); fr[1] = (short)f2bf(lo.y);
      fr[2] = (short)f2bf(lo.z); fr[3] = (short)f2bf(lo.w);
      fr[4] = (short)f2bf(hi.x); fr[5] = (short)f2bf(hi.y);
      fr[6] = (short)f2bf(hi.z); fr[7] = (short)f2bf(hi.w);
      Bf[ni] = fr;
    }
#pragma unroll
    for (int mi = 0; mi < 4; mi++)
#pragma unroll
      for (int ni = 0; ni < 4; ni++)
        acc[mi][ni] = __builtin_amdgcn_mfma_f32_16x16x32_bf16(
            Af[mi], Bf[ni], acc[mi][ni], 0, 0, 0);
  }

#pragma unroll
  for (int mi = 0; mi < 4; mi++) {
#pragma unroll
    for (int reg = 0; reg < 4; reg++) {
      size_t row = m0 + mi * 16 + quad * 4 + reg;
      float* orow = out + row * Cc + n0;
#pragma unroll
      for (int ni = 0; ni < 4; ni++)
        orow[ni * 16 + l15] = acc[mi][ni][reg];
    }
  }
}

// ---------------------------------------------------------------------------
extern "C" void kernel_launch(void* const* d_in, const int* in_sizes, int n_in,
                              void* d_out, int out_size, void* d_ws, size_t ws_size,
                              hipStream_t stream) {
  const float* x0      = (const float*)d_in[0];
  const float* center1 = (const float*)d_in[1];
  const float* W0      = (const float*)d_in[2];
  const float* b0      = (const float*)d_in[3];
  const float* W1      = (const float*)d_in[4];
  const float* b1      = (const float*)d_in[5];
  const float* Wm      = (const float*)d_in[6];
  const float* bm      = (const float*)d_in[7];
  const float* alpha   = (const float*)d_in[8];
  const float* beta    = (const float*)d_in[9];
  float* out = (float*)d_out;
  float* ws  = (float*)d_ws;

  float* xn   = ws;                              // 16 MB: x0p, then dispatched in-place
  float* cpn  = xn + (size_t)Nn * Ll * Cc;       // 1 MB
  float* cval = cpn + (size_t)Nn * FC * Ss * SC; // 1 MB  (total 18 MB)

  proj_mfma_k<<<dim3(576), dim3(256), 0, stream>>>(
      x0, W0, b0, center1, W1, b1, xn, cpn, cval);
  sim_k<<<dim3(32 * 64), dim3(256), 0, stream>>>(xn, cpn, cval, alpha, beta);
  out_mfma_k<<<dim3(256), dim3(256), 0, stream>>>(xn, Wm, bm, out);
}

// Round 9
// 148.199 us; speedup vs baseline: 1.2865x; 1.0085x over previous
//
#include <hip/hip_runtime.h>
#include <math.h>

// Problem constants (fixed by setup_inputs)
#define Nn 4
#define Ll 4096
#define Ss 256
#define Cc 256
#define FC 8
#define SC 32

typedef __attribute__((ext_vector_type(8))) short short8;     // 8 bf16 frag
typedef __attribute__((ext_vector_type(8))) _Float16 half8;   // 8 f16 frag
typedef __attribute__((ext_vector_type(4))) float f32x4;      // MFMA acc

__device__ __forceinline__ unsigned short f2bf(float x) {   // RTNE f32->bf16
  unsigned int u = __float_as_uint(x);
  return (unsigned short)((u + 0x7FFFu + ((u >> 16) & 1u)) >> 16);
}

// ---------------------------------------------------------------------------
// fp32-accurate f16-split on matrix cores (verified absmax 0.0078).
// x = hi + lo/2048 + eps, |eps| <= 2^-22 |x|.
// ROUND-19: round-17's async gload_lds pipeline gained only 45->35us.
// Cause (guide m97): __syncthreads makes hipcc emit s_waitcnt vmcnt(0)
// lgkmcnt(0) BEFORE s_barrier -- draining the just-issued next-tile loads
// every iteration (8 x ~600cy exposed DMA latency). Fix: RAW
// __builtin_amdgcn_s_barrier() + explicit waits so the counted vmcnt(6)
// survives the barrier (8-phase-template discipline):
//   B1: vmcnt(6) [own tile landed; next 6 in flight] -> s_barrier
//   B2: lgkmcnt(0) [ds_reads retired] -> s_barrier [safe to overwrite]
// sched_barrier(0) fences prevent hoisting (rule #18). Never vmcnt(0) in
// the main loop.
// ---------------------------------------------------------------------------
__device__ __forceinline__ void split8v(float4 a, float4 b,
                                        half8& hi, half8& lo) {
  float v[8] = {a.x, a.y, a.z, a.w, b.x, b.y, b.z, b.w};
#pragma unroll
  for (int i = 0; i < 8; i++) {
    float x = v[i];
    _Float16 h = (_Float16)x;          // v_cvt_f16_f32 (RTNE)
    float r = (x - (float)h) * 2048.f; // exact residual, pre-scaled
    hi[i] = h;
    lo[i] = (_Float16)r;
  }
}

// stage one 128x32 A-tile + 64x32 B-tile (fp32) into LDS, 6 gload/wave.
// chunk c = 8 rows; lane (lr=l>>3, l8=l&7) loads row 8c+lr, 16B-chunk
// (l8^lr) -> lands at linear LDS byte c*1024 + lane*16 (swizzled layout).
#define STAGE(Abuf, Bbuf, K0)                                               \
  {                                                                         \
    _Pragma("unroll")                                                       \
    for (int j = 0; j < 4; j++) {                                           \
      int c = wave * 4 + j;                                                 \
      const float* g = Ag + (m0blk + 8 * c + lr) * Cc + (K0) + scol;        \
      __builtin_amdgcn_global_load_lds(                                     \
          (const __attribute__((address_space(1))) void*)g,                 \
          (__attribute__((address_space(3))) void*)((Abuf) + c * 256),      \
          16, 0, 0);                                                        \
    }                                                                       \
    _Pragma("unroll")                                                       \
    for (int j = 0; j < 2; j++) {                                           \
      int c = wave * 2 + j;                                                 \
      const float* g =                                                      \
          Bg + (size_t)(n0blk + 8 * c + lr) * Cc + (K0) + scol;             \
      __builtin_amdgcn_global_load_lds(                                     \
          (const __attribute__((address_space(1))) void*)g,                 \
          (__attribute__((address_space(3))) void*)((Bbuf) + c * 256),      \
          16, 0, 0);                                                        \
    }                                                                       \
  }

// one K=32 step: 12 ds_read_b128 (XOR-swizzled) + 6 splits + 24 MFMA.
#define KSTEP(Ac, Bc)                                                       \
  {                                                                         \
    half8 Bh[2], Bl[2];                                                     \
    _Pragma("unroll")                                                       \
    for (int ni = 0; ni < 2; ni++) {                                        \
      int rw = bR0 + ni * 16 + l15;                                         \
      int rb = rw * 32, xs = rw & 7;                                        \
      float4 f0 = *(const float4*)&(Bc)[rb + (((quad * 2) ^ xs) << 2)];     \
      float4 f1 = *(const float4*)&(Bc)[rb + (((quad * 2 + 1) ^ xs) << 2)]; \
      split8v(f0, f1, Bh[ni], Bl[ni]);                                      \
    }                                                                       \
    _Pragma("unroll")                                                       \
    for (int mi = 0; mi < 4; mi++) {                                        \
      int rw = aR0 + mi * 16 + l15;                                         \
      int rb = rw * 32, xs = rw & 7;                                        \
      float4 f0 = *(const float4*)&(Ac)[rb + (((quad * 2) ^ xs) << 2)];     \
      float4 f1 = *(const float4*)&(Ac)[rb + (((quad * 2 + 1) ^ xs) << 2)]; \
      half8 Ah, Al;                                                         \
      split8v(f0, f1, Ah, Al);                                              \
      _Pragma("unroll")                                                     \
      for (int ni = 0; ni < 2; ni++) {                                      \
        acc1[mi][ni] = __builtin_amdgcn_mfma_f32_16x16x32_f16(              \
            Ah, Bh[ni], acc1[mi][ni], 0, 0, 0);                             \
        acc2[mi][ni] = __builtin_amdgcn_mfma_f32_16x16x32_f16(              \
            Ah, Bl[ni], acc2[mi][ni], 0, 0, 0);                             \
        acc2[mi][ni] = __builtin_amdgcn_mfma_f32_16x16x32_f16(              \
            Al, Bh[ni], acc2[mi][ni], 0, 0, 0);                             \
      }                                                                     \
    }                                                                       \
  }

// ---------------------------------------------------------------------------
// Fused projections. Blocks 0..511: xn = x0 @ W0^T + b0 (M=16384, N=256,
// 128 row-tiles x 4 col-tiles; rt=b&127 -> the 4 col-tiles of a row-tile
// share b mod 8 = same XCD, 2MB A-set in its L2). Blocks 512..575:
// c1 = center1 @ W1^T + b1 (M=1024, N=512) with split/l2norm epilogue ->
// cpn (normalized point half), cval (raw value half). Wave tile 64x32:
// n0w multiple of 32 -> entirely in one half.
// ---------------------------------------------------------------------------
__global__ __launch_bounds__(256) void proj_mfma_k(
    const float* __restrict__ x0, const float* __restrict__ W0,
    const float* __restrict__ b0, const float* __restrict__ center1,
    const float* __restrict__ W1, const float* __restrict__ b1,
    float* __restrict__ xn, float* __restrict__ cpn, float* __restrict__ cval) {
  __shared__ float As[2][128 * 32];   // 32 KB (2 x 16 KB)
  __shared__ float Bs[2][64 * 32];    // 16 KB (2 x  8 KB)
  int t = threadIdx.x;
  int wave = t >> 6, lane = t & 63;
  int quad = lane >> 4, l15 = lane & 15;
  int l8 = lane & 7, lr = lane >> 3;        // lr in [0,8)
  int scol = (l8 ^ lr) << 2;                // pre-swizzled source col (floats)
  int b = blockIdx.x;

  const float *Ag, *Bg, *bias;
  size_t m0blk;
  int n0blk;
  bool isX = (b < 512);
  if (isX) {
    int rt = b & 127, cb = b >> 7;
    m0blk = (size_t)rt * 128;
    n0blk = cb * 64;
    Ag = x0; Bg = W0; bias = b0;
  } else {
    int b2 = b - 512;
    m0blk = (size_t)(b2 >> 3) * 128;
    n0blk = (b2 & 7) * 64;                  // N=512
    Ag = center1; Bg = W1; bias = b1;
  }

  int n0w = n0blk + (wave >> 1) * 32;       // wave's output cols
  int aR0 = (wave & 1) * 64;                // wave's LDS A row base
  int bR0 = (wave >> 1) * 32;               // wave's LDS B row base

  f32x4 acc1[4][2], acc2[4][2];
#pragma unroll
  for (int ni = 0; ni < 2; ni++) {
    float bv = bias[n0w + ni * 16 + l15];
    f32x4 ci = {bv, bv, bv, bv};
    f32x4 zz = {0.f, 0.f, 0.f, 0.f};
#pragma unroll
    for (int mi = 0; mi < 4; mi++) { acc1[mi][ni] = ci; acc2[mi][ni] = zz; }
  }

  float* Ac = &As[0][0]; float* An = &As[1][0];
  float* Bc = &Bs[0][0]; float* Bn = &Bs[1][0];
  STAGE(Ac, Bc, 0);
#pragma unroll 1
  for (int kt = 0; kt < 8; kt++) {
    if (kt < 7) {
      STAGE(An, Bn, (kt + 1) * 32);
      asm volatile("s_waitcnt vmcnt(6)" ::: "memory");  // kt's 6 landed; next 6 in flight
    } else {
      asm volatile("s_waitcnt vmcnt(0)" ::: "memory");  // epilogue drain
    }
    __builtin_amdgcn_sched_barrier(0);
    __builtin_amdgcn_s_barrier();      // RAW barrier: counted vmcnt survives
    __builtin_amdgcn_sched_barrier(0);
    KSTEP(Ac, Bc);
    asm volatile("s_waitcnt lgkmcnt(0)" ::: "memory");  // ds_reads retired
    __builtin_amdgcn_sched_barrier(0);
    __builtin_amdgcn_s_barrier();      // safe to overwrite buffers next iter
    __builtin_amdgcn_sched_barrier(0);
    float* tp;
    tp = Ac; Ac = An; An = tp;
    tp = Bc; Bc = Bn; Bn = tp;
  }

  if (isX) {
    size_t m0 = m0blk + aR0;
#pragma unroll
    for (int mi = 0; mi < 4; mi++) {
#pragma unroll
      for (int reg = 0; reg < 4; reg++) {
        size_t row = m0 + mi * 16 + quad * 4 + reg;
        float* orow = xn + row * Cc + n0w;
#pragma unroll
        for (int ni = 0; ni < 2; ni++)
          orow[ni * 16 + l15] =
              acc1[mi][ni][reg] + acc2[mi][ni][reg] * (1.f / 2048.f);
      }
    }
  } else {
    int f = n0w >> 6;                  // fiber
    bool point = (n0w & 32) == 0;      // cols (n0w&63)+0..31
    int m0 = (int)m0blk + aR0;
#pragma unroll
    for (int mi = 0; mi < 4; mi++) {
#pragma unroll
      for (int reg = 0; reg < 4; reg++) {
        int row = m0 + mi * 16 + quad * 4 + reg;   // 0..1023 = nI*256+s
        int nI = row >> 8, s = row & 255;
        float v0 = acc1[mi][0][reg] + acc2[mi][0][reg] * (1.f / 2048.f);
        float v1 = acc1[mi][1][reg] + acc2[mi][1][reg] * (1.f / 2048.f);
        size_t base = (((size_t)nI * FC + f) * Ss + s) * SC;
        if (point) {
          float ss = v0 * v0 + v1 * v1;    // 2 elems/lane x 16 lanes = 32
          ss += __shfl_xor(ss, 1, 64);
          ss += __shfl_xor(ss, 2, 64);
          ss += __shfl_xor(ss, 4, 64);
          ss += __shfl_xor(ss, 8, 64);     // full row norm in every lane
          float rin = 1.f / fmaxf(sqrtf(ss), 1e-12f);
          cpn[base + l15] = v0 * rin;
          cpn[base + 16 + l15] = v1 * rin;
        } else {
          cval[base + l15] = v0;
          cval[base + 16 + l15] = v1;
        }
      }
    }
  }
}

// ---------------------------------------------------------------------------
// sim on matrix cores (round-14, measured-good; UNCHANGED).
// Block: one (nf, 64-l-row tile); 4 waves x 16 l-rows; all 256 centers.
// Centers split ONCE per block into LDS [quad][256] half8 planes (32KB).
// ---------------------------------------------------------------------------
__global__ __launch_bounds__(256) void sim_k(
    float* __restrict__ xn, const float* __restrict__ cpn,
    const float* __restrict__ cval, const float* __restrict__ alphap,
    const float* __restrict__ betap) {
  __shared__ half8 BhS[4][256];   // [k-quad][s] hi planes, 16 KB
  __shared__ half8 BlS[4][256];   // lo planes, 16 KB
  int t = threadIdx.x;
  int wave = t >> 6, lane = t & 63;
  int quad = lane >> 4, l15 = lane & 15;
  int lt = blockIdx.x & 63;
  int nf = blockIdx.x >> 6;        // 0..31
  int f = nf & 7, nI = nf >> 3;
  int l0 = lt * 64;
  const float* cp = cpn + (size_t)nf * Ss * SC;

  // ---- stage + split all 256 centers: thread t = center row s ----
  {
    int s = t;
    float4 va[8];
#pragma unroll
    for (int q8 = 0; q8 < 8; q8++)
      va[q8] = *(const float4*)(cp + (size_t)s * SC + q8 * 4);
#pragma unroll
    for (int q = 0; q < 4; q++) {
      half8 h, l;
      split8v(va[2 * q], va[2 * q + 1], h, l);
      BhS[q][s] = h;
      BlS[q][s] = l;
    }
  }

  // ---- A: load own row slice, l2-normalize, split ----
  half8 Ah, Al;
  {
    const float* xrow =
        xn + ((size_t)nI * Ll + l0 + wave * 16 + l15) * Cc + f * SC + quad * 8;
    float4 a0 = *(const float4*)xrow;
    float4 a1 = *(const float4*)(xrow + 4);
    float ssq = a0.x * a0.x + a0.y * a0.y + a0.z * a0.z + a0.w * a0.w +
                a1.x * a1.x + a1.y * a1.y + a1.z * a1.z + a1.w * a1.w;
    ssq += __shfl_xor(ssq, 16, 64);   // reduce across the 4 quads
    ssq += __shfl_xor(ssq, 32, 64);   // (lanes sharing l15)
    float rin = 1.f / fmaxf(sqrtf(ssq), 1e-12f);
    a0.x *= rin; a0.y *= rin; a0.z *= rin; a0.w *= rin;
    a1.x *= rin; a1.y *= rin; a1.z *= rin; a1.w *= rin;
    split8v(a0, a1, Ah, Al);
  }

  __syncthreads();   // center planes visible

  float a = alphap[0], bt = betap[0];
  float best[4];
  int bi[4];
#pragma unroll
  for (int r = 0; r < 4; r++) { best[r] = -3.0e38f; bi[r] = 0; }

  // ---- 16 s-fragments: 2 ds_read_b128 + 3 MFMA each ----
#pragma unroll
  for (int j = 0; j < 16; j++) {
    half8 bh = BhS[quad][j * 16 + l15];
    half8 bl = BlS[quad][j * 16 + l15];
    f32x4 z = {0.f, 0.f, 0.f, 0.f};
    f32x4 c1 = __builtin_amdgcn_mfma_f32_16x16x32_f16(Ah, bh, z, 0, 0, 0);
    f32x4 c2 = __builtin_amdgcn_mfma_f32_16x16x32_f16(Ah, bl, z, 0, 0, 0);
    c2 = __builtin_amdgcn_mfma_f32_16x16x32_f16(Al, bh, c2, 0, 0, 0);
    int s = j * 16 + l15;
#pragma unroll
    for (int r = 0; r < 4; r++) {
      float v = c1[r] + c2[r] * (1.f / 2048.f);
      float tv = fmaf(a, v, bt);
      if (tv > best[r]) { best[r] = tv; bi[r] = s; }
    }
  }

  // ---- cross-lane argmax (16 l15-lanes per quad), gather, write ----
#pragma unroll
  for (int r = 0; r < 4; r++) {
    float bv = best[r];
    int ix = bi[r];
#pragma unroll
    for (int m = 1; m <= 8; m <<= 1) {
      float ov = __shfl_xor(bv, m, 64);
      int oi = __shfl_xor(ix, m, 64);
      if (ov > bv || (ov == bv && oi < ix)) { bv = ov; ix = oi; }
    }
    float mv = 1.f / (1.f + expf(-bv));
    const float* cvp = cval + ((size_t)nf * Ss + ix) * SC;
    float* orow =
        xn + ((size_t)nI * Ll + l0 + wave * 16 + quad * 4 + r) * Cc + f * SC;
    orow[l15] = cvp[l15] * mv;
    orow[l15 + 16] = cvp[l15 + 16] * mv;
  }
}

// ---------------------------------------------------------------------------
// out = dispatched @ Wm^T + bm via bf16 MFMA, NO LDS.        (UNCHANGED)
// ---------------------------------------------------------------------------
__global__ __launch_bounds__(256) void out_mfma_k(
    const float* __restrict__ xn, const float* __restrict__ Wm,
    const float* __restrict__ bm, float* __restrict__ out) {
  int t = threadIdx.x;
  int wave = t >> 6, lane = t & 63;
  int quad = lane >> 4, l15 = lane & 15;
  size_t m0 = (size_t)(blockIdx.x >> 1) * 128 + (wave & 1) * 64;
  int n0 = (blockIdx.x & 1) * 128 + (wave >> 1) * 64;

  f32x4 acc[4][4];
#pragma unroll
  for (int ni = 0; ni < 4; ni++) {
    float bv = bm[n0 + ni * 16 + l15];
    f32x4 ci = {bv, bv, bv, bv};
#pragma unroll
    for (int mi = 0; mi < 4; mi++) acc[mi][ni] = ci;
  }

  for (int kt = 0; kt < 8; kt++) {
    int k0 = kt * 32 + quad * 8;
    short8 Af[4], Bf[4];
#pragma unroll
    for (int mi = 0; mi < 4; mi++) {
      const float* p = xn + (m0 + mi * 16 + l15) * Cc + k0;
      float4 lo = *(const float4*)p;
      float4 hi = *(const float4*)(p + 4);
      short8 fr;
      fr[0] = (short)f2bf(lo.x); fr[1] = (short)f2bf(lo.y);
      fr[2] = (short)f2bf(lo.z); fr[3] = (short)f2bf(lo.w);
      fr[4] = (short)f2bf(hi.x); fr[5] = (short)f2bf(hi.y);
      fr[6] = (short)f2bf(hi.z); fr[7] = (short)f2bf(hi.w);
      Af[mi] = fr;
    }
#pragma unroll
    for (int ni = 0; ni < 4; ni++) {
      const float* p = Wm + (size_t)(n0 + ni * 16 + l15) * Cc + k0;
      float4 lo = *(const float4*)p;
      float4 hi = *(const float4*)(p + 4);
      short8 fr;
      fr[0] = (short)f2bf(lo.x); fr[1] = (short)f2bf(lo.y);
      fr[2] = (short)f2bf(lo.z); fr[3] = (short)f2bf(lo.w);
      fr[4] = (short)f2bf(hi.x); fr[5] = (short)f2bf(hi.y);
      fr[6] = (short)f2bf(hi.z); fr[7] = (short)f2bf(hi.w);
      Bf[ni] = fr;
    }
#pragma unroll
    for (int mi = 0; mi < 4; mi++)
#pragma unroll
      for (int ni = 0; ni < 4; ni++)
        acc[mi][ni] = __builtin_amdgcn_mfma_f32_16x16x32_bf16(
            Af[mi], Bf[ni], acc[mi][ni], 0, 0, 0);
  }

#pragma unroll
  for (int mi = 0; mi < 4; mi++) {
#pragma unroll
    for (int reg = 0; reg < 4; reg++) {
      size_t row = m0 + mi * 16 + quad * 4 + reg;
      float* orow = out + row * Cc + n0;
#pragma unroll
      for (int ni = 0; ni < 4; ni++)
        orow[ni * 16 + l15] = acc[mi][ni][reg];
    }
  }
}

// ---------------------------------------------------------------------------
extern "C" void kernel_launch(void* const* d_in, const int* in_sizes, int n_in,
                              void* d_out, int out_size, void* d_ws, size_t ws_size,
                              hipStream_t stream) {
  const float* x0      = (const float*)d_in[0];
  const float* center1 = (const float*)d_in[1];
  const float* W0      = (const float*)d_in[2];
  const float* b0      = (const float*)d_in[3];
  const float* W1      = (const float*)d_in[4];
  const float* b1      = (const float*)d_in[5];
  const float* Wm      = (const float*)d_in[6];
  const float* bm      = (const float*)d_in[7];
  const float* alpha   = (const float*)d_in[8];
  const float* beta    = (const float*)d_in[9];
  float* out = (float*)d_out;
  float* ws  = (float*)d_ws;

  float* xn   = ws;                              // 16 MB: x0p, then dispatched in-place
  float* cpn  = xn + (size_t)Nn * Ll * Cc;       // 1 MB
  float* cval = cpn + (size_t)Nn * FC * Ss * SC; // 1 MB  (total 18 MB)

  proj_mfma_k<<<dim3(576), dim3(256), 0, stream>>>(
      x0, W0, b0, center1, W1, b1, xn, cpn, cval);
  sim_k<<<dim3(32 * 64), dim3(256), 0, stream>>>(xn, cpn, cval, alpha, beta);
  out_mfma_k<<<dim3(256), dim3(256), 0, stream>>>(xn, Wm, bm, out);
}